// Round 2
// baseline (496.644 us; speedup 1.0000x reference)
//
#include <hip/hip_runtime.h>

#define N_NODES 50000
#define N_EDGES 800000
#define HID 128

typedef _Float16 f16;
typedef _Float16 half8 __attribute__((ext_vector_type(8)));
typedef _Float16 half4 __attribute__((ext_vector_type(4)));
typedef _Float16 half2v __attribute__((ext_vector_type(2)));
typedef float f32x4 __attribute__((ext_vector_type(4)));
typedef float f32x2 __attribute__((ext_vector_type(2)));

// ---- CSR-path workspace layout (bytes). P (f16 [50000][256]) and mi (f32) live in d_out. ----
#define OFF_MEDGE  0UL             // 800000*128*2 = 204,800,000 (CSR-ordered messages)
#define OFF_H16C   204800000UL     // 12,800,000
#define OFF_WC     217600000UL     // packed weights: 204,800
#define OFF_CNT    217804800UL     // 50176*4 = 200,704
#define OFF_OFFS   218005504UL     // 200,704
#define OFF_CUR    218206208UL     // 200,704
#define OFF_PERM   218406912UL     // 800000*4 = 3,200,000
#define CSR_TOTAL  221606912UL

// ---- fallback (atomic-path) layout ----
#define OFF_MI   0UL
#define OFF_H16  25600000UL
#define OFF_W    38400000UL

#define WB1 0
#define WB2 36864
#define WN1 53248
#define WN2 86016

#define TS 136   // T tile stride (aliased into S buffer)
#define YS 264   // node Y tile stride (256 + pad)
#define SS 132   // S tile stride (f32), mult of 4 for b128, 2-way-free bank pattern
#define AS 40    // attr tile stride (f16): 24 attr + 8 zero + pad

#define EB 32    // edges per block

// pack weights into B-fragment layout; also zero cnt (CSR path)
__global__ __launch_bounds__(256) void pack_weights(
    const float* __restrict__ We1, const float* __restrict__ We2,
    const float* __restrict__ Wn1, const float* __restrict__ Wn2,
    f16* __restrict__ W, int* __restrict__ cnt) {
  int i = blockIdx.x * 256 + threadIdx.x;   // 0..102399
  if (cnt && i < 50176) cnt[i] = 0;
  if (i < 36864) {                          // We1 (rows permuted: h first, attr last)
    int j = i & 7, n = (i >> 3) & 127, qk = i >> 10;
    int k = qk * 8 + j;
    float v = 0.f;
    if (k < 256) v = We1[(24 + k) * 128 + n];
    else if (k < 280) v = We1[(k - 256) * 128 + n];
    W[WB1 + i] = (f16)v;
  } else if (i < 53248) {                   // We2
    int l = i - 36864;
    int j = l & 7, n = (l >> 3) & 127, qk = l >> 10;
    W[WB2 + l] = (f16)We2[(qk * 8 + j) * 128 + n];
  } else if (i < 86016) {                   // Wn1
    int l = i - 53248;
    int j = l & 7, n = (l >> 3) & 127, qk = l >> 10;
    W[WN1 + l] = (f16)Wn1[(qk * 8 + j) * 128 + n];
  } else if (i < 102400) {                  // Wn2
    int l = i - 86016;
    int j = l & 7, n = (l >> 3) & 127, qk = l >> 10;
    W[WN2 + l] = (f16)Wn2[(qk * 8 + j) * 128 + n];
  }
}

// h f32 -> f16 (800K threads); fused degree histogram (CSR path)
__global__ __launch_bounds__(256) void convert_hist(
    const float* __restrict__ h, const int* __restrict__ eidx,
    f16* __restrict__ h16, int* __restrict__ cnt) {
  int i = blockIdx.x * 256 + threadIdx.x;   // 0..799999 exactly
  const float4* src = (const float4*)h + (size_t)i * 2;
  float4 a = src[0], b = src[1];
  half8 v = {(f16)a.x, (f16)a.y, (f16)a.z, (f16)a.w,
             (f16)b.x, (f16)b.y, (f16)b.z, (f16)b.w};
  *((half8*)h16 + i) = v;
  if (cnt) atomicAdd(&cnt[eidx[i]], 1);
}

// single-block exclusive scan of 50176 counts -> offs, cur
__global__ __launch_bounds__(256) void scan_kernel(const int* __restrict__ cnt,
                                                   int* __restrict__ offs, int* __restrict__ cur) {
  __shared__ int sb[256];
  int t = threadIdx.x;
  int base = t * 196;               // 256*196 = 50176
  int s = 0;
  for (int k = 0; k < 196; ++k) s += cnt[base + k];
  sb[t] = s;
  __syncthreads();
  for (int off = 1; off < 256; off <<= 1) {
    int v = (t >= off) ? sb[t - off] : 0;
    __syncthreads();
    sb[t] += v;
    __syncthreads();
  }
  int run = sb[t] - s;
  for (int k = 0; k < 196; ++k) {
    int c = cnt[base + k];
    offs[base + k] = run;
    cur[base + k] = run;
    run += c;
  }
}

// CSR permutation: perm[csr_pos] = edge id
__global__ __launch_bounds__(256) void fill_perm(
    const int* __restrict__ eidx, int* __restrict__ cur, int* __restrict__ perm) {
  int i = blockIdx.x * 256 + threadIdx.x;   // 0..799999 exactly
  int p = atomicAdd(&cur[eidx[i]], 1);
  perm[p] = i;
}

// ==== precompute: P[n][0:128] = h[n] @ We1[24:152], P[n][128:256] = h[n] @ We1[152:280]
//      (f16 out). Uses the SAME packed WB1 (k=0..127 -> Pd block, k=128..255 -> Ps block). ====
__global__ __launch_bounds__(256, 4) void precompute_kernel(
    const f16* __restrict__ h16, const f16* __restrict__ Wp, f16* __restrict__ P) {
  __shared__ f16 Y[64 * 136];
  int t = threadIdx.x;
  int n0 = blockIdx.x * 64;
  {
    int rb = t >> 4, ch = t & 15;
    for (int p = 0; p < 4; ++p) {
      int r = p * 16 + rb;
      int g = n0 + r; if (g >= N_NODES) g = N_NODES - 1;
      *(uint4*)&Y[r * 136 + ch * 8] = *(const uint4*)(h16 + (size_t)g * HID + ch * 8);
    }
  }
  __syncthreads();
  int w = t >> 6, lane = t & 63, q = lane >> 4, c = lane & 15;
  int colBase = w * 32;
  const f16* B = Wp + WB1 + ((size_t)(q * 128 + colBase + c)) * 8;
  f32x4 aD[4][2], aS[4][2];
  #pragma unroll
  for (int mt = 0; mt < 4; ++mt) {
    aD[mt][0] = (f32x4){0, 0, 0, 0}; aD[mt][1] = (f32x4){0, 0, 0, 0};
    aS[mt][0] = (f32x4){0, 0, 0, 0}; aS[mt][1] = (f32x4){0, 0, 0, 0};
  }
  #pragma unroll
  for (int ks = 0; ks < 4; ++ks) {
    half8 bD0 = *(const half8*)(B + ks * 4096);
    half8 bD1 = *(const half8*)(B + ks * 4096 + 128);
    half8 bS0 = *(const half8*)(B + (ks + 4) * 4096);
    half8 bS1 = *(const half8*)(B + (ks + 4) * 4096 + 128);
    #pragma unroll
    for (int mt = 0; mt < 4; ++mt) {
      half8 a = *(const half8*)&Y[(mt * 16 + c) * 136 + ks * 32 + q * 8];
      aD[mt][0] = __builtin_amdgcn_mfma_f32_16x16x32_f16(a, bD0, aD[mt][0], 0, 0, 0);
      aD[mt][1] = __builtin_amdgcn_mfma_f32_16x16x32_f16(a, bD1, aD[mt][1], 0, 0, 0);
      aS[mt][0] = __builtin_amdgcn_mfma_f32_16x16x32_f16(a, bS0, aS[mt][0], 0, 0, 0);
      aS[mt][1] = __builtin_amdgcn_mfma_f32_16x16x32_f16(a, bS1, aS[mt][1], 0, 0, 0);
    }
  }
  #pragma unroll
  for (int mt = 0; mt < 4; ++mt)
    #pragma unroll
    for (int r = 0; r < 4; ++r) {
      int g = n0 + mt * 16 + q * 4 + r;
      if (g < N_NODES) {
        f16* o = P + (size_t)g * 256 + colBase + c;
        o[0]        = (f16)aD[mt][0][r];
        o[16]       = (f16)aD[mt][1][r];
        o[128]      = (f16)aS[mt][0][r];
        o[128 + 16] = (f16)aS[mt][1][r];
      }
    }
}

// ==== edge kernel: CSR-ordered (perm) edges. Layer1 = attr@Wa (K=32 MFMA) + gathered
//      Pd[dst]+Ps[src] (f32 LDS). medge write is sequential (slot == csr position). ====
__global__ __launch_bounds__(256, 8) void edge_kernel(
    const f16* __restrict__ P, const int* __restrict__ eidx,
    const float* __restrict__ eattr,
    const f16* __restrict__ Wp, const float* __restrict__ be1,
    const float* __restrict__ be2,
    const float* __restrict__ Wg, const float* __restrict__ bg,
    float* __restrict__ mi, f16* __restrict__ medge, const int* __restrict__ perm) {
  __shared__ float S[EB * SS];       // 16,896B  (f32 Pd+Ps sums; T aliases this)
  __shared__ f16 A[EB * AS];         // 2,560B   (attr, 24 + 8 zeros)
  __shared__ float part[EB * 4];
  __shared__ float eijL[EB];
  __shared__ int dstL[EB];           // fallback: atomic target
  int t = threadIdx.x;
  int e0 = blockIdx.x * EB;

  if (!medge && t < EB) dstL[t] = eidx[e0 + t];

  // ---- stage S = Pd[dst] + Ps[src] as f32 ----
  {
    int rb = t >> 4, ch = t & 15;
    for (int p = 0; p < 2; ++p) {
      int r = p * 16 + rb;
      int e = perm ? perm[e0 + r] : (e0 + r);
      int d = eidx[e];
      int s = eidx[N_EDGES + e];
      half8 pd = *(const half8*)(P + (size_t)d * 256 + ch * 8);
      half8 ps = *(const half8*)(P + (size_t)s * 256 + 128 + ch * 8);
      f32x4 lo = {(float)pd[0] + (float)ps[0], (float)pd[1] + (float)ps[1],
                  (float)pd[2] + (float)ps[2], (float)pd[3] + (float)ps[3]};
      f32x4 hi = {(float)pd[4] + (float)ps[4], (float)pd[5] + (float)ps[5],
                  (float)pd[6] + (float)ps[6], (float)pd[7] + (float)ps[7]};
      *(f32x4*)&S[r * SS + ch * 8]     = lo;
      *(f32x4*)&S[r * SS + ch * 8 + 4] = hi;
    }
  }
  // ---- stage edge_attr (cols 0..23), zeros 24..31 ----
  if (t < 192) {
    int el = t / 6, kk = t % 6;
    int e = perm ? perm[e0 + el] : (e0 + el);
    float4 f = *(const float4*)(eattr + (size_t)e * 24 + kk * 4);
    half4 hv = {(f16)f.x, (f16)f.y, (f16)f.z, (f16)f.w};
    *(half4*)&A[el * AS + kk * 4] = hv;
  }
  if (t < EB) { uint4 z = {0, 0, 0, 0}; *(uint4*)&A[t * AS + 24] = z; }
  __syncthreads();

  int w = t >> 6, lane = t & 63, q = lane >> 4, c = lane & 15;
  int colBase = w * 32;

  // ---- layer 1: attr GEMM (K=32, WB1 block k=256..287) + S add ----
  f32x4 acc[2][2];
  {
    float b0 = be1[colBase + c], b1 = be1[colBase + 16 + c];
    #pragma unroll
    for (int mt = 0; mt < 2; ++mt) {
      acc[mt][0] = (f32x4){b0, b0, b0, b0};
      acc[mt][1] = (f32x4){b1, b1, b1, b1};
    }
  }
  {
    const f16* bA = Wp + WB1 + 32768 + ((size_t)(q * 128 + colBase + c)) * 8;
    half8 b0f = *(const half8*)(bA);
    half8 b1f = *(const half8*)(bA + 128);
    #pragma unroll
    for (int mt = 0; mt < 2; ++mt) {
      half8 a = *(const half8*)&A[(mt * 16 + c) * AS + q * 8];
      acc[mt][0] = __builtin_amdgcn_mfma_f32_16x16x32_f16(a, b0f, acc[mt][0], 0, 0, 0);
      acc[mt][1] = __builtin_amdgcn_mfma_f32_16x16x32_f16(a, b1f, acc[mt][1], 0, 0, 0);
    }
  }
  #pragma unroll
  for (int mt = 0; mt < 2; ++mt)
    #pragma unroll
    for (int r = 0; r < 4; ++r) {
      const float* sr = &S[(mt * 16 + q * 4 + r) * SS + colBase + c];
      acc[mt][0][r] += sr[0];
      acc[mt][1][r] += sr[16];
    }

  const f16* bp2base = Wp + WB2 + ((size_t)(q * 128 + colBase + c)) * 8;
  half8 d0 = *(const half8*)(bp2base);
  half8 d1 = *(const half8*)(bp2base + 128);

  __syncthreads();
  f16* T = (f16*)S;   // alias (S dead from here)
  #pragma unroll
  for (int mt = 0; mt < 2; ++mt)
    #pragma unroll
    for (int nt = 0; nt < 2; ++nt)
      #pragma unroll
      for (int r = 0; r < 4; ++r) {
        float v = acc[mt][nt][r];
        T[(mt * 16 + q * 4 + r) * TS + colBase + nt * 16 + c] = (f16)(v > 0.f ? v : 0.f);
      }
  __syncthreads();

  // ---- layer 2 ----
  f32x4 m2[2][2];
  {
    float b0 = be2[colBase + c], b1 = be2[colBase + 16 + c];
    #pragma unroll
    for (int mt = 0; mt < 2; ++mt) {
      m2[mt][0] = (f32x4){b0, b0, b0, b0};
      m2[mt][1] = (f32x4){b1, b1, b1, b1};
    }
  }
  #pragma unroll
  for (int kk = 0; kk < 4; ++kk) {
    half8 n0, n1;
    if (kk < 3) {
      n0 = *(const half8*)(bp2base + (kk + 1) * 4096);
      n1 = *(const half8*)(bp2base + (kk + 1) * 4096 + 128);
    }
    #pragma unroll
    for (int mt = 0; mt < 2; ++mt) {
      half8 a = *(const half8*)&T[(mt * 16 + c) * TS + kk * 32 + q * 8];
      m2[mt][0] = __builtin_amdgcn_mfma_f32_16x16x32_f16(a, d0, m2[mt][0], 0, 0, 0);
      m2[mt][1] = __builtin_amdgcn_mfma_f32_16x16x32_f16(a, d1, m2[mt][1], 0, 0, 0);
    }
    d0 = n0; d1 = n1;
  }

  // ---- relu + gate ----
  float wg0 = Wg[colBase + c], wg1 = Wg[colBase + 16 + c];
  float pd[2][4];
  #pragma unroll
  for (int mt = 0; mt < 2; ++mt)
    #pragma unroll
    for (int r = 0; r < 4; ++r) {
      float v0 = m2[mt][0][r]; v0 = v0 > 0.f ? v0 : 0.f; m2[mt][0][r] = v0;
      float v1 = m2[mt][1][r]; v1 = v1 > 0.f ? v1 : 0.f; m2[mt][1][r] = v1;
      pd[mt][r] = v0 * wg0 + v1 * wg1;
    }
  #pragma unroll
  for (int off = 1; off < 16; off <<= 1)
    #pragma unroll
    for (int mt = 0; mt < 2; ++mt)
      #pragma unroll
      for (int r = 0; r < 4; ++r)
        pd[mt][r] += __shfl_xor(pd[mt][r], off, 64);
  if (c == 0)
    #pragma unroll
    for (int mt = 0; mt < 2; ++mt)
      #pragma unroll
      for (int r = 0; r < 4; ++r)
        part[(mt * 16 + q * 4 + r) * 4 + w] = pd[mt][r];
  __syncthreads();
  if (t < EB) {
    float s = part[t * 4] + part[t * 4 + 1] + part[t * 4 + 2] + part[t * 4 + 3] + bg[0];
    eijL[t] = 1.f / (1.f + __expf(-s));
  }
  __syncthreads();

  if (medge) {
    #pragma unroll
    for (int mt = 0; mt < 2; ++mt)
      #pragma unroll
      for (int r = 0; r < 4; ++r) {
        int el = mt * 16 + q * 4 + r;
        float ev = eijL[el];
        T[el * TS + colBase + c]      = (f16)(m2[mt][0][r] * ev);
        T[el * TS + colBase + 16 + c] = (f16)(m2[mt][1][r] * ev);
      }
    __syncthreads();
    int r = t >> 3, p = t & 7;      // 8 threads/row, 32B each; slot == csr position -> sequential
    uint4* dst = (uint4*)(medge + ((size_t)(e0 + r)) * HID + p * 16);
    const uint4* s2 = (const uint4*)&T[r * TS + p * 16];
    dst[0] = s2[0]; dst[1] = s2[1];
  } else {
    #pragma unroll
    for (int mt = 0; mt < 2; ++mt)
      #pragma unroll
      for (int r = 0; r < 4; ++r) {
        int el = mt * 16 + q * 4 + r;
        float ev = eijL[el];
        float* base = mi + (size_t)dstL[el] * HID + colBase + c;
        atomicAdd(base,      m2[mt][0][r] * ev);
        atomicAdd(base + 16, m2[mt][1][r] * ev);
      }
  }
}

// ==== seg-sum: one WAVE per node; lane l owns cols [2l,2l+1]. Fully-coalesced 256B
//      wave reads of consecutive memory; uniform trip count. ====
__global__ __launch_bounds__(256) void segsum_kernel(
    const f16* __restrict__ medge, const int* __restrict__ offs,
    const int* __restrict__ cnt, float* __restrict__ mi) {
  int t = threadIdx.x;
  int g = blockIdx.x * 4 + (t >> 6);      // 12500 blocks * 4 waves = 50000 nodes
  int l = t & 63;
  int start = offs[g], deg = cnt[g];
  const f16* base = medge + (size_t)start * HID + 2 * l;
  float ax = 0.f, ay = 0.f;
  #pragma unroll 4
  for (int i = 0; i < deg; ++i) {
    half2v v = *(const half2v*)(base + (size_t)i * HID);
    ax += (float)v[0]; ay += (float)v[1];
  }
  f32x2 o = {ax, ay};
  *(f32x2*)(mi + (size_t)g * HID + 2 * l) = o;
}

// ==== node MLP kernel: reads f32 mi + h16, writes out. mi MAY alias out:
//      each block reads only its own rows (before barrier) and writes them after. ====
__global__ __launch_bounds__(256, 4) void node_kernel(
    const float* mi, const f16* __restrict__ h16,
    const f16* __restrict__ Wp, const float* __restrict__ bn1,
    const float* __restrict__ bn2, float* out) {
  __shared__ f16 Y[64 * YS];
  int t = threadIdx.x;
  int n0 = blockIdx.x * 64;
  {
    int rb = t >> 4, ch = t & 15;
    for (int p = 0; p < 4; ++p) {
      int r = p * 16 + rb;
      int g = n0 + r; if (g >= N_NODES) g = N_NODES - 1;
      const float4* s = (const float4*)(mi + (size_t)g * HID + ch * 8);
      float4 a = s[0], b = s[1];
      half8 v = {(f16)a.x, (f16)a.y, (f16)a.z, (f16)a.w,
                 (f16)b.x, (f16)b.y, (f16)b.z, (f16)b.w};
      *(half8*)&Y[r * YS + ch * 8] = v;
      *(uint4*)&Y[r * YS + 128 + ch * 8] = *(const uint4*)(h16 + (size_t)g * HID + ch * 8);
    }
  }
  __syncthreads();
  int w = t >> 6, lane = t & 63, q = lane >> 4, c = lane & 15;
  int colBase = w * 32;
  const f16* BN1 = Wp + WN1;
  const f16* BN2 = Wp + WN2;
  f32x4 acc[4][2];
  {
    float b0 = bn1[colBase + c], b1 = bn1[colBase + 16 + c];
    #pragma unroll
    for (int mt = 0; mt < 4; ++mt) {
      acc[mt][0] = (f32x4){b0, b0, b0, b0};
      acc[mt][1] = (f32x4){b1, b1, b1, b1};
    }
  }
  const f16* bn1base = BN1 + ((size_t)(q * 128 + colBase + c)) * 8;
  half8 bf0 = *(const half8*)(bn1base);
  half8 bf1 = *(const half8*)(bn1base + 128);
  #pragma unroll
  for (int ks = 0; ks < 8; ++ks) {
    half8 nb0, nb1;
    if (ks < 7) {
      nb0 = *(const half8*)(bn1base + (ks + 1) * 4096);
      nb1 = *(const half8*)(bn1base + (ks + 1) * 4096 + 128);
    }
    #pragma unroll
    for (int mt = 0; mt < 4; ++mt) {
      half8 a = *(const half8*)&Y[(mt * 16 + c) * YS + ks * 32 + q * 8];
      acc[mt][0] = __builtin_amdgcn_mfma_f32_16x16x32_f16(a, bf0, acc[mt][0], 0, 0, 0);
      acc[mt][1] = __builtin_amdgcn_mfma_f32_16x16x32_f16(a, bf1, acc[mt][1], 0, 0, 0);
    }
    bf0 = nb0; bf1 = nb1;
  }
  const f16* bn2base = BN2 + ((size_t)(q * 128 + colBase + c)) * 8;
  half8 d0 = *(const half8*)(bn2base);
  half8 d1 = *(const half8*)(bn2base + 128);
  __syncthreads();
  f16* T = Y;
  #pragma unroll
  for (int mt = 0; mt < 4; ++mt)
    #pragma unroll
    for (int nt = 0; nt < 2; ++nt)
      #pragma unroll
      for (int r = 0; r < 4; ++r) {
        float v = acc[mt][nt][r];
        T[(mt * 16 + q * 4 + r) * TS + colBase + nt * 16 + c] = (f16)(v > 0.f ? v : 0.f);
      }
  __syncthreads();
  f32x4 m2[4][2];
  {
    float b0 = bn2[colBase + c], b1 = bn2[colBase + 16 + c];
    #pragma unroll
    for (int mt = 0; mt < 4; ++mt) {
      m2[mt][0] = (f32x4){b0, b0, b0, b0};
      m2[mt][1] = (f32x4){b1, b1, b1, b1};
    }
  }
  #pragma unroll
  for (int kk = 0; kk < 4; ++kk) {
    half8 n0, n1;
    if (kk < 3) {
      n0 = *(const half8*)(bn2base + (kk + 1) * 4096);
      n1 = *(const half8*)(bn2base + (kk + 1) * 4096 + 128);
    }
    #pragma unroll
    for (int mt = 0; mt < 4; ++mt) {
      half8 a = *(const half8*)&T[(mt * 16 + c) * TS + kk * 32 + q * 8];
      m2[mt][0] = __builtin_amdgcn_mfma_f32_16x16x32_f16(a, d0, m2[mt][0], 0, 0, 0);
      m2[mt][1] = __builtin_amdgcn_mfma_f32_16x16x32_f16(a, d1, m2[mt][1], 0, 0, 0);
    }
    d0 = n0; d1 = n1;
  }
  #pragma unroll
  for (int mt = 0; mt < 4; ++mt)
    #pragma unroll
    for (int r = 0; r < 4; ++r) {
      int g = n0 + mt * 16 + q * 4 + r;
      if (g < N_NODES) {
        float* o = out + (size_t)g * HID + colBase + c;
        o[0]  = m2[mt][0][r];
        o[16] = m2[mt][1][r];
      }
    }
}

extern "C" void kernel_launch(void* const* d_in, const int* in_sizes, int n_in,
                              void* d_out, int out_size, void* d_ws, size_t ws_size,
                              hipStream_t stream) {
  const float* h    = (const float*)d_in[0];
  const int*   eidx = (const int*)d_in[1];
  const float* eattr= (const float*)d_in[2];
  const float* We1  = (const float*)d_in[3];
  const float* be1  = (const float*)d_in[4];
  const float* We2  = (const float*)d_in[5];
  const float* be2  = (const float*)d_in[6];
  const float* Wg   = (const float*)d_in[7];
  const float* bg   = (const float*)d_in[8];
  const float* Wn1  = (const float*)d_in[9];
  const float* bn1  = (const float*)d_in[10];
  const float* Wn2  = (const float*)d_in[11];
  const float* bn2  = (const float*)d_in[12];
  float* out = (float*)d_out;
  char* ws = (char*)d_ws;

  if (ws_size >= CSR_TOTAL) {
    f16* medge = (f16*)(ws + OFF_MEDGE);
    f16* h16   = (f16*)(ws + OFF_H16C);
    f16* Wp    = (f16*)(ws + OFF_WC);
    int* cnt   = (int*)(ws + OFF_CNT);
    int* offs  = (int*)(ws + OFF_OFFS);
    int* cur   = (int*)(ws + OFF_CUR);
    int* perm  = (int*)(ws + OFF_PERM);
    f16* P     = (f16*)out;   // P dead before segsum overwrites out with mi
    float* mi  = out;

    pack_weights<<<400, 256, 0, stream>>>(We1, We2, Wn1, Wn2, Wp, cnt);
    convert_hist<<<3125, 256, 0, stream>>>(h, eidx, h16, cnt);
    scan_kernel<<<1, 256, 0, stream>>>(cnt, offs, cur);
    precompute_kernel<<<(N_NODES + 63) / 64, 256, 0, stream>>>(h16, Wp, P);
    fill_perm<<<3125, 256, 0, stream>>>(eidx, cur, perm);
    edge_kernel<<<N_EDGES / EB, 256, 0, stream>>>(P, eidx, eattr, Wp, be1, be2,
                                                  Wg, bg, nullptr, medge, perm);
    segsum_kernel<<<N_NODES / 4, 256, 0, stream>>>(medge, offs, cnt, mi);
    node_kernel<<<(N_NODES + 63) / 64, 256, 0, stream>>>(mi, h16, Wp, bn1, bn2, out);
  } else {
    float* mi  = (float*)(ws + OFF_MI);
    f16*   h16 = (f16*)(ws + OFF_H16);
    f16*   Wp  = (f16*)(ws + OFF_W);
    f16*   P   = (f16*)out;   // P dead before node_kernel writes out

    hipMemsetAsync(mi, 0, (size_t)N_NODES * HID * sizeof(float), stream);
    pack_weights<<<400, 256, 0, stream>>>(We1, We2, Wn1, Wn2, Wp, nullptr);
    convert_hist<<<3125, 256, 0, stream>>>(h, eidx, h16, nullptr);
    precompute_kernel<<<(N_NODES + 63) / 64, 256, 0, stream>>>(h16, Wp, P);
    edge_kernel<<<N_EDGES / EB, 256, 0, stream>>>(P, eidx, eattr, Wp, be1, be2,
                                                  Wg, bg, mi, nullptr, nullptr);
    node_kernel<<<(N_NODES + 63) / 64, 256, 0, stream>>>(mi, h16, Wp, bn1, bn2, out);
  }
}

// Round 3
// 424.056 us; speedup vs baseline: 1.1712x; 1.1712x over previous
//
#include <hip/hip_runtime.h>

#define N_NODES 50000
#define N_EDGES 800000
#define HID 128

typedef _Float16 f16;
typedef _Float16 half8 __attribute__((ext_vector_type(8)));
typedef _Float16 half4 __attribute__((ext_vector_type(4)));
typedef _Float16 half2v __attribute__((ext_vector_type(2)));
typedef float f32x4 __attribute__((ext_vector_type(4)));
typedef float f32x2 __attribute__((ext_vector_type(2)));

// ---- CSR-path workspace layout (bytes). P (f16 [50000][256]) lives in d_out. ----
#define OFF_MI     0UL             // 50000*128*4 = 25,600,000 (f32 aggregate, memset 0)
#define OFF_H16C   25600000UL      // 12,800,000
#define OFF_WC     38400000UL      // packed weights: 204,800
#define OFF_CNT    38604800UL      // 50176*4 = 200,704
#define OFF_OFFS   38805504UL      // 200,704
#define OFF_CUR    39006208UL      // 200,704
#define OFF_PERM   39206912UL      // 800000*4 = 3,200,000
#define CSR_TOTAL  42406912UL

// ---- fallback (atomic-path) layout ----
#define OFF_FMI  0UL
#define OFF_FH16 25600000UL
#define OFF_FW   38400000UL

#define WB1 0
#define WB2 36864
#define WN1 53248
#define WN2 86016

#define TS 136   // T tile stride (f16, aliased into S buffer)
#define YS 264   // node Y tile stride (256 + pad)
#define SS 132   // S tile stride (f32)
#define AS 40    // attr tile stride (f16): 24 attr + 8 zero + pad

#define EB 32    // edges per block

// pack weights into B-fragment layout; also zero cnt (CSR path)
__global__ __launch_bounds__(256) void pack_weights(
    const float* __restrict__ We1, const float* __restrict__ We2,
    const float* __restrict__ Wn1, const float* __restrict__ Wn2,
    f16* __restrict__ W, int* __restrict__ cnt) {
  int i = blockIdx.x * 256 + threadIdx.x;   // 0..102399
  if (cnt && i < 50176) cnt[i] = 0;
  if (i < 36864) {                          // We1 (rows permuted: h first, attr last)
    int j = i & 7, n = (i >> 3) & 127, qk = i >> 10;
    int k = qk * 8 + j;
    float v = 0.f;
    if (k < 256) v = We1[(24 + k) * 128 + n];
    else if (k < 280) v = We1[(k - 256) * 128 + n];
    W[WB1 + i] = (f16)v;
  } else if (i < 53248) {                   // We2
    int l = i - 36864;
    int j = l & 7, n = (l >> 3) & 127, qk = l >> 10;
    W[WB2 + l] = (f16)We2[(qk * 8 + j) * 128 + n];
  } else if (i < 86016) {                   // Wn1
    int l = i - 53248;
    int j = l & 7, n = (l >> 3) & 127, qk = l >> 10;
    W[WN1 + l] = (f16)Wn1[(qk * 8 + j) * 128 + n];
  } else if (i < 102400) {                  // Wn2
    int l = i - 86016;
    int j = l & 7, n = (l >> 3) & 127, qk = l >> 10;
    W[WN2 + l] = (f16)Wn2[(qk * 8 + j) * 128 + n];
  }
}

// single-block exclusive scan of 50176 counts -> offs, cur
__global__ __launch_bounds__(256) void scan_kernel(const int* __restrict__ cnt,
                                                   int* __restrict__ offs, int* __restrict__ cur) {
  __shared__ int sb[256];
  int t = threadIdx.x;
  int base = t * 196;               // 256*196 = 50176
  int s = 0;
  for (int k = 0; k < 196; ++k) s += cnt[base + k];
  sb[t] = s;
  __syncthreads();
  for (int off = 1; off < 256; off <<= 1) {
    int v = (t >= off) ? sb[t - off] : 0;
    __syncthreads();
    sb[t] += v;
    __syncthreads();
  }
  int run = sb[t] - s;
  for (int k = 0; k < 196; ++k) {
    int c = cnt[base + k];
    offs[base + k] = run;
    cur[base + k] = run;
    run += c;
  }
}

// CSR permutation: perm[csr_pos] = edge id
__global__ __launch_bounds__(256) void fill_perm(
    const int* __restrict__ eidx, int* __restrict__ cur, int* __restrict__ perm) {
  int i = blockIdx.x * 256 + threadIdx.x;   // 0..799999 exactly
  int p = atomicAdd(&cur[eidx[i]], 1);
  perm[p] = i;
}

// ==== precompute: converts h f32->f16 (writes h16), degree histogram, and
//      P[n][0:128] = h[n]@We1[24:152], P[n][128:256] = h[n]@We1[152:280] (f16). ====
__global__ __launch_bounds__(256, 4) void precompute_kernel(
    const float* __restrict__ h, const int* __restrict__ eidx,
    const f16* __restrict__ Wp, f16* __restrict__ P,
    f16* __restrict__ h16, int* __restrict__ cnt) {
  __shared__ f16 Y[64 * 136];
  int t = threadIdx.x;
  int n0 = blockIdx.x * 64;
  {
    int rb = t >> 4, ch = t & 15;
    for (int p = 0; p < 4; ++p) {
      int r = p * 16 + rb;
      int g = n0 + r; if (g >= N_NODES) g = N_NODES - 1;
      const float4* s4 = (const float4*)(h + (size_t)g * HID + ch * 8);
      float4 a = s4[0], b = s4[1];
      half8 v = {(f16)a.x, (f16)a.y, (f16)a.z, (f16)a.w,
                 (f16)b.x, (f16)b.y, (f16)b.z, (f16)b.w};
      *(half8*)&Y[r * 136 + ch * 8] = v;
      *(half8*)(h16 + (size_t)g * HID + ch * 8) = v;
    }
  }
  // fused degree histogram (grid-stride over edges)
  if (cnt) {
    for (int i = blockIdx.x * 256 + t; i < N_EDGES; i += gridDim.x * 256)
      atomicAdd(&cnt[eidx[i]], 1);
  }
  __syncthreads();
  int w = t >> 6, lane = t & 63, q = lane >> 4, c = lane & 15;
  int colBase = w * 32;
  const f16* B = Wp + WB1 + ((size_t)(q * 128 + colBase + c)) * 8;
  f32x4 aD[4][2], aS[4][2];
  #pragma unroll
  for (int mt = 0; mt < 4; ++mt) {
    aD[mt][0] = (f32x4){0, 0, 0, 0}; aD[mt][1] = (f32x4){0, 0, 0, 0};
    aS[mt][0] = (f32x4){0, 0, 0, 0}; aS[mt][1] = (f32x4){0, 0, 0, 0};
  }
  #pragma unroll
  for (int ks = 0; ks < 4; ++ks) {
    half8 bD0 = *(const half8*)(B + ks * 4096);
    half8 bD1 = *(const half8*)(B + ks * 4096 + 128);
    half8 bS0 = *(const half8*)(B + (ks + 4) * 4096);
    half8 bS1 = *(const half8*)(B + (ks + 4) * 4096 + 128);
    #pragma unroll
    for (int mt = 0; mt < 4; ++mt) {
      half8 a = *(const half8*)&Y[(mt * 16 + c) * 136 + ks * 32 + q * 8];
      aD[mt][0] = __builtin_amdgcn_mfma_f32_16x16x32_f16(a, bD0, aD[mt][0], 0, 0, 0);
      aD[mt][1] = __builtin_amdgcn_mfma_f32_16x16x32_f16(a, bD1, aD[mt][1], 0, 0, 0);
      aS[mt][0] = __builtin_amdgcn_mfma_f32_16x16x32_f16(a, bS0, aS[mt][0], 0, 0, 0);
      aS[mt][1] = __builtin_amdgcn_mfma_f32_16x16x32_f16(a, bS1, aS[mt][1], 0, 0, 0);
    }
  }
  #pragma unroll
  for (int mt = 0; mt < 4; ++mt)
    #pragma unroll
    for (int r = 0; r < 4; ++r) {
      int g = n0 + mt * 16 + q * 4 + r;
      if (g < N_NODES) {
        f16* o = P + (size_t)g * 256 + colBase + c;
        o[0]        = (f16)aD[mt][0][r];
        o[16]       = (f16)aD[mt][1][r];
        o[128]      = (f16)aS[mt][0][r];
        o[128 + 16] = (f16)aS[mt][1][r];
      }
    }
}

// ==== edge kernel: CSR-ordered (perm) edges. Layer1 = attr@Wa (K=32 MFMA) + gathered
//      Pd[dst]+Ps[src]. CSR mode: in-block run-reduction over equal-dst rows ->
//      coalesced f32 atomicAdd row-sums into mi (no medge, no segsum). ====
__global__ __launch_bounds__(256, 8) void edge_kernel(
    const f16* __restrict__ P, const int* __restrict__ eidx,
    const float* __restrict__ eattr,
    const f16* __restrict__ Wp, const float* __restrict__ be1,
    const float* __restrict__ be2,
    const float* __restrict__ Wg, const float* __restrict__ bg,
    float* __restrict__ mi, const int* __restrict__ perm) {
  __shared__ float S[EB * SS];       // 16,896B  (f32 Pd+Ps sums; T aliases this)
  __shared__ f16 A[EB * AS];         // 2,560B   (attr, 24 + 8 zeros)
  __shared__ float part[EB * 4];
  __shared__ float eijL[EB];
  __shared__ int dstL[EB];
  int t = threadIdx.x;
  int e0 = blockIdx.x * EB;

  if (t < EB) {
    int e = perm ? perm[e0 + t] : (e0 + t);
    dstL[t] = eidx[e];
  }
  // ---- stage S = Pd[dst] + Ps[src] as f32 ----
  {
    int rb = t >> 4, ch = t & 15;
    for (int p = 0; p < 2; ++p) {
      int r = p * 16 + rb;
      int e = perm ? perm[e0 + r] : (e0 + r);
      int d = eidx[e];
      int s = eidx[N_EDGES + e];
      half8 pd = *(const half8*)(P + (size_t)d * 256 + ch * 8);
      half8 ps = *(const half8*)(P + (size_t)s * 256 + 128 + ch * 8);
      f32x4 lo = {(float)pd[0] + (float)ps[0], (float)pd[1] + (float)ps[1],
                  (float)pd[2] + (float)ps[2], (float)pd[3] + (float)ps[3]};
      f32x4 hi = {(float)pd[4] + (float)ps[4], (float)pd[5] + (float)ps[5],
                  (float)pd[6] + (float)ps[6], (float)pd[7] + (float)ps[7]};
      *(f32x4*)&S[r * SS + ch * 8]     = lo;
      *(f32x4*)&S[r * SS + ch * 8 + 4] = hi;
    }
  }
  // ---- stage edge_attr (cols 0..23), zeros 24..31 ----
  if (t < 192) {
    int el = t / 6, kk = t % 6;
    int e = perm ? perm[e0 + el] : (e0 + el);
    float4 f = *(const float4*)(eattr + (size_t)e * 24 + kk * 4);
    half4 hv = {(f16)f.x, (f16)f.y, (f16)f.z, (f16)f.w};
    *(half4*)&A[el * AS + kk * 4] = hv;
  }
  if (t < EB) { uint4 z = {0, 0, 0, 0}; *(uint4*)&A[t * AS + 24] = z; }
  __syncthreads();

  int w = t >> 6, lane = t & 63, q = lane >> 4, c = lane & 15;
  int colBase = w * 32;

  // ---- layer 1: attr GEMM (K=32, WB1 block k=256..287) + S add ----
  f32x4 acc[2][2];
  {
    float b0 = be1[colBase + c], b1 = be1[colBase + 16 + c];
    #pragma unroll
    for (int mt = 0; mt < 2; ++mt) {
      acc[mt][0] = (f32x4){b0, b0, b0, b0};
      acc[mt][1] = (f32x4){b1, b1, b1, b1};
    }
  }
  {
    const f16* bA = Wp + WB1 + 32768 + ((size_t)(q * 128 + colBase + c)) * 8;
    half8 b0f = *(const half8*)(bA);
    half8 b1f = *(const half8*)(bA + 128);
    #pragma unroll
    for (int mt = 0; mt < 2; ++mt) {
      half8 a = *(const half8*)&A[(mt * 16 + c) * AS + q * 8];
      acc[mt][0] = __builtin_amdgcn_mfma_f32_16x16x32_f16(a, b0f, acc[mt][0], 0, 0, 0);
      acc[mt][1] = __builtin_amdgcn_mfma_f32_16x16x32_f16(a, b1f, acc[mt][1], 0, 0, 0);
    }
  }
  #pragma unroll
  for (int mt = 0; mt < 2; ++mt)
    #pragma unroll
    for (int r = 0; r < 4; ++r) {
      const float* sr = &S[(mt * 16 + q * 4 + r) * SS + colBase + c];
      acc[mt][0][r] += sr[0];
      acc[mt][1][r] += sr[16];
    }

  const f16* bp2base = Wp + WB2 + ((size_t)(q * 128 + colBase + c)) * 8;
  half8 d0 = *(const half8*)(bp2base);
  half8 d1 = *(const half8*)(bp2base + 128);

  __syncthreads();
  f16* T = (f16*)S;   // alias (S dead from here)
  #pragma unroll
  for (int mt = 0; mt < 2; ++mt)
    #pragma unroll
    for (int nt = 0; nt < 2; ++nt)
      #pragma unroll
      for (int r = 0; r < 4; ++r) {
        float v = acc[mt][nt][r];
        T[(mt * 16 + q * 4 + r) * TS + colBase + nt * 16 + c] = (f16)(v > 0.f ? v : 0.f);
      }
  __syncthreads();

  // ---- layer 2 ----
  f32x4 m2[2][2];
  {
    float b0 = be2[colBase + c], b1 = be2[colBase + 16 + c];
    #pragma unroll
    for (int mt = 0; mt < 2; ++mt) {
      m2[mt][0] = (f32x4){b0, b0, b0, b0};
      m2[mt][1] = (f32x4){b1, b1, b1, b1};
    }
  }
  #pragma unroll
  for (int kk = 0; kk < 4; ++kk) {
    half8 n0, n1;
    if (kk < 3) {
      n0 = *(const half8*)(bp2base + (kk + 1) * 4096);
      n1 = *(const half8*)(bp2base + (kk + 1) * 4096 + 128);
    }
    #pragma unroll
    for (int mt = 0; mt < 2; ++mt) {
      half8 a = *(const half8*)&T[(mt * 16 + c) * TS + kk * 32 + q * 8];
      m2[mt][0] = __builtin_amdgcn_mfma_f32_16x16x32_f16(a, d0, m2[mt][0], 0, 0, 0);
      m2[mt][1] = __builtin_amdgcn_mfma_f32_16x16x32_f16(a, d1, m2[mt][1], 0, 0, 0);
    }
    d0 = n0; d1 = n1;
  }

  // ---- relu + gate ----
  float wg0 = Wg[colBase + c], wg1 = Wg[colBase + 16 + c];
  float pd[2][4];
  #pragma unroll
  for (int mt = 0; mt < 2; ++mt)
    #pragma unroll
    for (int r = 0; r < 4; ++r) {
      float v0 = m2[mt][0][r]; v0 = v0 > 0.f ? v0 : 0.f; m2[mt][0][r] = v0;
      float v1 = m2[mt][1][r]; v1 = v1 > 0.f ? v1 : 0.f; m2[mt][1][r] = v1;
      pd[mt][r] = v0 * wg0 + v1 * wg1;
    }
  #pragma unroll
  for (int off = 1; off < 16; off <<= 1)
    #pragma unroll
    for (int mt = 0; mt < 2; ++mt)
      #pragma unroll
      for (int r = 0; r < 4; ++r)
        pd[mt][r] += __shfl_xor(pd[mt][r], off, 64);
  if (c == 0)
    #pragma unroll
    for (int mt = 0; mt < 2; ++mt)
      #pragma unroll
      for (int r = 0; r < 4; ++r)
        part[(mt * 16 + q * 4 + r) * 4 + w] = pd[mt][r];
  __syncthreads();
  if (t < EB) {
    float s = part[t * 4] + part[t * 4 + 1] + part[t * 4 + 2] + part[t * 4 + 3] + bg[0];
    eijL[t] = 1.f / (1.f + __expf(-s));
  }
  __syncthreads();

  if (perm) {
    // ---- write gated rows to T, then run-reduce equal-dst rows -> atomicAdd mi ----
    #pragma unroll
    for (int mt = 0; mt < 2; ++mt)
      #pragma unroll
      for (int r = 0; r < 4; ++r) {
        int el = mt * 16 + q * 4 + r;
        float ev = eijL[el];
        T[el * TS + colBase + c]      = (f16)(m2[mt][0][r] * ev);
        T[el * TS + colBase + 16 + c] = (f16)(m2[mt][1][r] * ev);
      }
    __syncthreads();
    int col = t & 127, half = t >> 7;
    int r0 = half * 16;
    float acc2 = 0.f;
    int dprev = dstL[r0];
    #pragma unroll
    for (int r2 = 0; r2 < 16; ++r2) {
      int rr = r0 + r2;
      acc2 += (float)T[rr * TS + col];
      int dnext = (r2 == 15) ? -1 : dstL[rr + 1];
      if (dnext != dprev) {
        atomicAdd(&mi[(size_t)dprev * HID + col], acc2);
        acc2 = 0.f;
        dprev = dnext;
      }
    }
  } else {
    #pragma unroll
    for (int mt = 0; mt < 2; ++mt)
      #pragma unroll
      for (int r = 0; r < 4; ++r) {
        int el = mt * 16 + q * 4 + r;
        float ev = eijL[el];
        float* base = mi + (size_t)dstL[el] * HID + colBase + c;
        atomicAdd(base,      m2[mt][0][r] * ev);
        atomicAdd(base + 16, m2[mt][1][r] * ev);
      }
  }
}

// ==== node MLP kernel: reads f32 mi (ws) + h16, writes out (P dead by now). ====
__global__ __launch_bounds__(256, 4) void node_kernel(
    const float* __restrict__ mi, const f16* __restrict__ h16,
    const f16* __restrict__ Wp, const float* __restrict__ bn1,
    const float* __restrict__ bn2, float* __restrict__ out) {
  __shared__ f16 Y[64 * YS];
  int t = threadIdx.x;
  int n0 = blockIdx.x * 64;
  {
    int rb = t >> 4, ch = t & 15;
    for (int p = 0; p < 4; ++p) {
      int r = p * 16 + rb;
      int g = n0 + r; if (g >= N_NODES) g = N_NODES - 1;
      const float4* s = (const float4*)(mi + (size_t)g * HID + ch * 8);
      float4 a = s[0], b = s[1];
      half8 v = {(f16)a.x, (f16)a.y, (f16)a.z, (f16)a.w,
                 (f16)b.x, (f16)b.y, (f16)b.z, (f16)b.w};
      *(half8*)&Y[r * YS + ch * 8] = v;
      *(uint4*)&Y[r * YS + 128 + ch * 8] = *(const uint4*)(h16 + (size_t)g * HID + ch * 8);
    }
  }
  __syncthreads();
  int w = t >> 6, lane = t & 63, q = lane >> 4, c = lane & 15;
  int colBase = w * 32;
  const f16* BN1 = Wp + WN1;
  const f16* BN2 = Wp + WN2;
  f32x4 acc[4][2];
  {
    float b0 = bn1[colBase + c], b1 = bn1[colBase + 16 + c];
    #pragma unroll
    for (int mt = 0; mt < 4; ++mt) {
      acc[mt][0] = (f32x4){b0, b0, b0, b0};
      acc[mt][1] = (f32x4){b1, b1, b1, b1};
    }
  }
  const f16* bn1base = BN1 + ((size_t)(q * 128 + colBase + c)) * 8;
  half8 bf0 = *(const half8*)(bn1base);
  half8 bf1 = *(const half8*)(bn1base + 128);
  #pragma unroll
  for (int ks = 0; ks < 8; ++ks) {
    half8 nb0, nb1;
    if (ks < 7) {
      nb0 = *(const half8*)(bn1base + (ks + 1) * 4096);
      nb1 = *(const half8*)(bn1base + (ks + 1) * 4096 + 128);
    }
    #pragma unroll
    for (int mt = 0; mt < 4; ++mt) {
      half8 a = *(const half8*)&Y[(mt * 16 + c) * YS + ks * 32 + q * 8];
      acc[mt][0] = __builtin_amdgcn_mfma_f32_16x16x32_f16(a, bf0, acc[mt][0], 0, 0, 0);
      acc[mt][1] = __builtin_amdgcn_mfma_f32_16x16x32_f16(a, bf1, acc[mt][1], 0, 0, 0);
    }
    bf0 = nb0; bf1 = nb1;
  }
  const f16* bn2base = BN2 + ((size_t)(q * 128 + colBase + c)) * 8;
  half8 d0 = *(const half8*)(bn2base);
  half8 d1 = *(const half8*)(bn2base + 128);
  __syncthreads();
  f16* T = Y;
  #pragma unroll
  for (int mt = 0; mt < 4; ++mt)
    #pragma unroll
    for (int nt = 0; nt < 2; ++nt)
      #pragma unroll
      for (int r = 0; r < 4; ++r) {
        float v = acc[mt][nt][r];
        T[(mt * 16 + q * 4 + r) * TS + colBase + nt * 16 + c] = (f16)(v > 0.f ? v : 0.f);
      }
  __syncthreads();
  f32x4 m2[4][2];
  {
    float b0 = bn2[colBase + c], b1 = bn2[colBase + 16 + c];
    #pragma unroll
    for (int mt = 0; mt < 4; ++mt) {
      m2[mt][0] = (f32x4){b0, b0, b0, b0};
      m2[mt][1] = (f32x4){b1, b1, b1, b1};
    }
  }
  #pragma unroll
  for (int kk = 0; kk < 4; ++kk) {
    half8 n0, n1;
    if (kk < 3) {
      n0 = *(const half8*)(bn2base + (kk + 1) * 4096);
      n1 = *(const half8*)(bn2base + (kk + 1) * 4096 + 128);
    }
    #pragma unroll
    for (int mt = 0; mt < 4; ++mt) {
      half8 a = *(const half8*)&T[(mt * 16 + c) * TS + kk * 32 + q * 8];
      m2[mt][0] = __builtin_amdgcn_mfma_f32_16x16x32_f16(a, d0, m2[mt][0], 0, 0, 0);
      m2[mt][1] = __builtin_amdgcn_mfma_f32_16x16x32_f16(a, d1, m2[mt][1], 0, 0, 0);
    }
    d0 = n0; d1 = n1;
  }
  #pragma unroll
  for (int mt = 0; mt < 4; ++mt)
    #pragma unroll
    for (int r = 0; r < 4; ++r) {
      int g = n0 + mt * 16 + q * 4 + r;
      if (g < N_NODES) {
        float* o = out + (size_t)g * HID + colBase + c;
        o[0]  = m2[mt][0][r];
        o[16] = m2[mt][1][r];
      }
    }
}

extern "C" void kernel_launch(void* const* d_in, const int* in_sizes, int n_in,
                              void* d_out, int out_size, void* d_ws, size_t ws_size,
                              hipStream_t stream) {
  const float* h    = (const float*)d_in[0];
  const int*   eidx = (const int*)d_in[1];
  const float* eattr= (const float*)d_in[2];
  const float* We1  = (const float*)d_in[3];
  const float* be1  = (const float*)d_in[4];
  const float* We2  = (const float*)d_in[5];
  const float* be2  = (const float*)d_in[6];
  const float* Wg   = (const float*)d_in[7];
  const float* bg   = (const float*)d_in[8];
  const float* Wn1  = (const float*)d_in[9];
  const float* bn1  = (const float*)d_in[10];
  const float* Wn2  = (const float*)d_in[11];
  const float* bn2  = (const float*)d_in[12];
  float* out = (float*)d_out;
  char* ws = (char*)d_ws;

  if (ws_size >= CSR_TOTAL) {
    float* mi  = (float*)(ws + OFF_MI);
    f16* h16   = (f16*)(ws + OFF_H16C);
    f16* Wp    = (f16*)(ws + OFF_WC);
    int* cnt   = (int*)(ws + OFF_CNT);
    int* offs  = (int*)(ws + OFF_OFFS);
    int* cur   = (int*)(ws + OFF_CUR);
    int* perm  = (int*)(ws + OFF_PERM);
    f16* P     = (f16*)out;   // P dead before node_kernel writes out

    hipMemsetAsync(mi, 0, (size_t)N_NODES * HID * sizeof(float), stream);
    pack_weights<<<400, 256, 0, stream>>>(We1, We2, Wn1, Wn2, Wp, cnt);
    precompute_kernel<<<(N_NODES + 63) / 64, 256, 0, stream>>>(h, eidx, Wp, P, h16, cnt);
    scan_kernel<<<1, 256, 0, stream>>>(cnt, offs, cur);
    fill_perm<<<3125, 256, 0, stream>>>(eidx, cur, perm);
    edge_kernel<<<N_EDGES / EB, 256, 0, stream>>>(P, eidx, eattr, Wp, be1, be2,
                                                  Wg, bg, mi, perm);
    node_kernel<<<(N_NODES + 63) / 64, 256, 0, stream>>>(mi, h16, Wp, bn1, bn2, out);
  } else {
    float* mi  = (float*)(ws + OFF_FMI);
    f16*   h16 = (f16*)(ws + OFF_FH16);
    f16*   Wp  = (f16*)(ws + OFF_FW);
    f16*   P   = (f16*)out;   // P dead before node_kernel writes out

    hipMemsetAsync(mi, 0, (size_t)N_NODES * HID * sizeof(float), stream);
    pack_weights<<<400, 256, 0, stream>>>(We1, We2, Wn1, Wn2, Wp, nullptr);
    precompute_kernel<<<(N_NODES + 63) / 64, 256, 0, stream>>>(h, eidx, Wp, P, h16, nullptr);
    edge_kernel<<<N_EDGES / EB, 256, 0, stream>>>(P, eidx, eattr, Wp, be1, be2,
                                                  Wg, bg, mi, nullptr);
    node_kernel<<<(N_NODES + 63) / 64, 256, 0, stream>>>(mi, h16, Wp, bn1, bn2, out);
  }
}

// Round 4
// 404.572 us; speedup vs baseline: 1.2276x; 1.0482x over previous
//
#include <hip/hip_runtime.h>

#define N_NODES 50000
#define N_EDGES 800000
#define HID 128

typedef _Float16 f16;
typedef _Float16 half8 __attribute__((ext_vector_type(8)));
typedef _Float16 half4 __attribute__((ext_vector_type(4)));
typedef _Float16 half2v __attribute__((ext_vector_type(2)));
typedef float f32x4 __attribute__((ext_vector_type(4)));
typedef float f32x2 __attribute__((ext_vector_type(2)));

// ---- CSR-path workspace layout (bytes). P (f16 [50000][256]) lives in d_out. ----
#define OFF_MI     0UL             // 50000*128*4 = 25,600,000 (f32 aggregate, memset 0)
#define OFF_H16C   25600000UL      // 12,800,000
#define OFF_WC     38400000UL      // packed weights: 204,800
#define OFF_CNT    38604800UL      // 50176*4 = 200,704
#define OFF_CUR    38805504UL      // 200,704
#define OFF_PERM   39006208UL      // 800000*4 = 3,200,000
#define OFF_BT     42206208UL      // 64*4 = 256
#define CSR_TOTAL  42206464UL

// ---- fallback (atomic-path) layout ----
#define OFF_FMI  0UL
#define OFF_FH16 25600000UL
#define OFF_FW   38400000UL

#define WB1 0
#define WB2 36864
#define WN1 53248
#define WN2 86016

#define TS 136   // S16/T tile stride (f16)
#define YS 264   // node Y tile stride (256 + pad)
#define AS 40    // attr tile stride (f16): 24 attr + 8 zero + pad

#define EB 32    // edges per block

// pack weights into B-fragment layout; also zero cnt (CSR path)
__global__ __launch_bounds__(256) void pack_weights(
    const float* __restrict__ We1, const float* __restrict__ We2,
    const float* __restrict__ Wn1, const float* __restrict__ Wn2,
    f16* __restrict__ W, int* __restrict__ cnt) {
  int i = blockIdx.x * 256 + threadIdx.x;   // 0..102399
  if (cnt && i < 50176) cnt[i] = 0;
  if (i < 36864) {                          // We1 (rows permuted: h first, attr last)
    int j = i & 7, n = (i >> 3) & 127, qk = i >> 10;
    int k = qk * 8 + j;
    float v = 0.f;
    if (k < 256) v = We1[(24 + k) * 128 + n];
    else if (k < 280) v = We1[(k - 256) * 128 + n];
    W[WB1 + i] = (f16)v;
  } else if (i < 53248) {                   // We2
    int l = i - 36864;
    int j = l & 7, n = (l >> 3) & 127, qk = l >> 10;
    W[WB2 + l] = (f16)We2[(qk * 8 + j) * 128 + n];
  } else if (i < 86016) {                   // Wn1
    int l = i - 53248;
    int j = l & 7, n = (l >> 3) & 127, qk = l >> 10;
    W[WN1 + l] = (f16)Wn1[(qk * 8 + j) * 128 + n];
  } else if (i < 102400) {                  // Wn2
    int l = i - 86016;
    int j = l & 7, n = (l >> 3) & 127, qk = l >> 10;
    W[WN2 + l] = (f16)Wn2[(qk * 8 + j) * 128 + n];
  }
}

// ==== coalesced 3-stage scan of cnt[50176] -> cur (exclusive prefix) ====
// stage A: 49 blocks x 1024 elems; int4 per thread; local exclusive scan -> cur, block total -> bt
__global__ __launch_bounds__(256) void scanA(const int* __restrict__ cnt,
                                             int* __restrict__ cur, int* __restrict__ bt) {
  __shared__ int wsum[4];
  int t = threadIdx.x, b = blockIdx.x;
  int base = b * 1024 + t * 4;
  int4 v = *(const int4*)(cnt + base);
  int s = v.x + v.y + v.z + v.w;
  int lane = t & 63, w = t >> 6;
  int inc = s;
  #pragma unroll
  for (int off = 1; off < 64; off <<= 1) {
    int u = __shfl_up(inc, off, 64);
    if (lane >= off) inc += u;
  }
  if (lane == 63) wsum[w] = inc;
  __syncthreads();
  int wbase = 0;
  for (int i = 0; i < w; ++i) wbase += wsum[i];
  int excl = wbase + inc - s;
  int4 o;
  o.x = excl; o.y = excl + v.x; o.z = o.y + v.y; o.w = o.z + v.z;
  *(int4*)(cur + base) = o;
  if (t == 255) bt[b] = wbase + inc;
}

// stage B: single wave exclusive scan of 49 block totals (in place)
__global__ __launch_bounds__(64) void scanB(int* __restrict__ bt) {
  int l = threadIdx.x;
  int v = (l < 49) ? bt[l] : 0;
  int inc = v;
  #pragma unroll
  for (int off = 1; off < 64; off <<= 1) {
    int u = __shfl_up(inc, off, 64);
    if (l >= off) inc += u;
  }
  if (l < 49) bt[l] = inc - v;
}

// stage C: add block base
__global__ __launch_bounds__(256) void scanC(int* __restrict__ cur, const int* __restrict__ bt) {
  int t = threadIdx.x, b = blockIdx.x;
  int base = b * 1024 + t * 4;
  int add = bt[b];
  int4 o = *(int4*)(cur + base);
  o.x += add; o.y += add; o.z += add; o.w += add;
  *(int4*)(cur + base) = o;
}

// CSR permutation: perm[csr_pos] = edge id
__global__ __launch_bounds__(256) void fill_perm(
    const int* __restrict__ eidx, int* __restrict__ cur, int* __restrict__ perm) {
  int i = blockIdx.x * 256 + threadIdx.x;   // 0..799999 exactly
  int p = atomicAdd(&cur[eidx[i]], 1);
  perm[p] = i;
}

// ==== precompute: converts h f32->f16 (writes h16), degree histogram, and
//      P[n][0:128] = h[n]@We1[24:152], P[n][128:256] = h[n]@We1[152:280] (f16). ====
__global__ __launch_bounds__(256, 4) void precompute_kernel(
    const float* __restrict__ h, const int* __restrict__ eidx,
    const f16* __restrict__ Wp, f16* __restrict__ P,
    f16* __restrict__ h16, int* __restrict__ cnt) {
  __shared__ f16 Y[64 * 136];
  int t = threadIdx.x;
  int n0 = blockIdx.x * 64;
  {
    int rb = t >> 4, ch = t & 15;
    for (int p = 0; p < 4; ++p) {
      int r = p * 16 + rb;
      int g = n0 + r; if (g >= N_NODES) g = N_NODES - 1;
      const float4* s4 = (const float4*)(h + (size_t)g * HID + ch * 8);
      float4 a = s4[0], b = s4[1];
      half8 v = {(f16)a.x, (f16)a.y, (f16)a.z, (f16)a.w,
                 (f16)b.x, (f16)b.y, (f16)b.z, (f16)b.w};
      *(half8*)&Y[r * 136 + ch * 8] = v;
      *(half8*)(h16 + (size_t)g * HID + ch * 8) = v;
    }
  }
  // fused degree histogram (grid-stride over edges)
  if (cnt) {
    for (int i = blockIdx.x * 256 + t; i < N_EDGES; i += gridDim.x * 256)
      atomicAdd(&cnt[eidx[i]], 1);
  }
  __syncthreads();
  int w = t >> 6, lane = t & 63, q = lane >> 4, c = lane & 15;
  int colBase = w * 32;
  const f16* B = Wp + WB1 + ((size_t)(q * 128 + colBase + c)) * 8;
  f32x4 aD[4][2], aS[4][2];
  #pragma unroll
  for (int mt = 0; mt < 4; ++mt) {
    aD[mt][0] = (f32x4){0, 0, 0, 0}; aD[mt][1] = (f32x4){0, 0, 0, 0};
    aS[mt][0] = (f32x4){0, 0, 0, 0}; aS[mt][1] = (f32x4){0, 0, 0, 0};
  }
  #pragma unroll
  for (int ks = 0; ks < 4; ++ks) {
    half8 bD0 = *(const half8*)(B + ks * 4096);
    half8 bD1 = *(const half8*)(B + ks * 4096 + 128);
    half8 bS0 = *(const half8*)(B + (ks + 4) * 4096);
    half8 bS1 = *(const half8*)(B + (ks + 4) * 4096 + 128);
    #pragma unroll
    for (int mt = 0; mt < 4; ++mt) {
      half8 a = *(const half8*)&Y[(mt * 16 + c) * 136 + ks * 32 + q * 8];
      aD[mt][0] = __builtin_amdgcn_mfma_f32_16x16x32_f16(a, bD0, aD[mt][0], 0, 0, 0);
      aD[mt][1] = __builtin_amdgcn_mfma_f32_16x16x32_f16(a, bD1, aD[mt][1], 0, 0, 0);
      aS[mt][0] = __builtin_amdgcn_mfma_f32_16x16x32_f16(a, bS0, aS[mt][0], 0, 0, 0);
      aS[mt][1] = __builtin_amdgcn_mfma_f32_16x16x32_f16(a, bS1, aS[mt][1], 0, 0, 0);
    }
  }
  #pragma unroll
  for (int mt = 0; mt < 4; ++mt)
    #pragma unroll
    for (int r = 0; r < 4; ++r) {
      int g = n0 + mt * 16 + q * 4 + r;
      if (g < N_NODES) {
        f16* o = P + (size_t)g * 256 + colBase + c;
        o[0]        = (f16)aD[mt][0][r];
        o[16]       = (f16)aD[mt][1][r];
        o[128]      = (f16)aS[mt][0][r];
        o[128 + 16] = (f16)aS[mt][1][r];
      }
    }
}

// ==== edge kernel: CSR-ordered (perm) edges. Layer1 = attr@Wa (K=32 MFMA) + gathered
//      f16 (Pd[dst]+Ps[src]) staged via packed adds. CSR mode: in-block run-reduction
//      over equal-dst rows -> coalesced f32 atomicAdd row-sums into mi. ====
__global__ __launch_bounds__(256, 8) void edge_kernel(
    const f16* __restrict__ P, const int* __restrict__ eidx,
    const float* __restrict__ eattr,
    const f16* __restrict__ Wp, const float* __restrict__ be1,
    const float* __restrict__ be2,
    const float* __restrict__ Wg, const float* __restrict__ bg,
    float* __restrict__ mi, const int* __restrict__ perm) {
  __shared__ f16 S16[EB * TS];       // 8,704B  (f16 Pd+Ps sums; T aliases this)
  __shared__ f16 A[EB * AS];         // 2,560B  (attr, 24 + 8 zeros)
  __shared__ float part[EB * 4];
  __shared__ float eijL[EB];
  __shared__ int dstL[EB];
  int t = threadIdx.x;
  int e0 = blockIdx.x * EB;

  if (t < EB) {
    int e = perm ? perm[e0 + t] : (e0 + t);
    dstL[t] = eidx[e];
  }
  // ---- stage S16 = Pd[dst] + Ps[src] (f16, packed adds) ----
  {
    int rb = t >> 4, ch = t & 15;
    for (int p = 0; p < 2; ++p) {
      int r = p * 16 + rb;
      int e = perm ? perm[e0 + r] : (e0 + r);
      int d = eidx[e];
      int s = eidx[N_EDGES + e];
      half8 pd = *(const half8*)(P + (size_t)d * 256 + ch * 8);
      half8 ps = *(const half8*)(P + (size_t)s * 256 + 128 + ch * 8);
      *(half8*)&S16[r * TS + ch * 8] = pd + ps;
    }
  }
  // ---- stage edge_attr (cols 0..23), zeros 24..31 ----
  if (t < 192) {
    int el = t / 6, kk = t % 6;
    int e = perm ? perm[e0 + el] : (e0 + el);
    float4 f = *(const float4*)(eattr + (size_t)e * 24 + kk * 4);
    half4 hv = {(f16)f.x, (f16)f.y, (f16)f.z, (f16)f.w};
    *(half4*)&A[el * AS + kk * 4] = hv;
  }
  if (t < EB) { uint4 z = {0, 0, 0, 0}; *(uint4*)&A[t * AS + 24] = z; }
  __syncthreads();

  int w = t >> 6, lane = t & 63, q = lane >> 4, c = lane & 15;
  int colBase = w * 32;

  // ---- layer 1: attr GEMM (K=32, WB1 block k=256..287) + S16 add ----
  f32x4 acc[2][2];
  {
    float b0 = be1[colBase + c], b1 = be1[colBase + 16 + c];
    #pragma unroll
    for (int mt = 0; mt < 2; ++mt) {
      acc[mt][0] = (f32x4){b0, b0, b0, b0};
      acc[mt][1] = (f32x4){b1, b1, b1, b1};
    }
  }
  {
    const f16* bA = Wp + WB1 + 32768 + ((size_t)(q * 128 + colBase + c)) * 8;
    half8 b0f = *(const half8*)(bA);
    half8 b1f = *(const half8*)(bA + 128);
    #pragma unroll
    for (int mt = 0; mt < 2; ++mt) {
      half8 a = *(const half8*)&A[(mt * 16 + c) * AS + q * 8];
      acc[mt][0] = __builtin_amdgcn_mfma_f32_16x16x32_f16(a, b0f, acc[mt][0], 0, 0, 0);
      acc[mt][1] = __builtin_amdgcn_mfma_f32_16x16x32_f16(a, b1f, acc[mt][1], 0, 0, 0);
    }
  }
  #pragma unroll
  for (int mt = 0; mt < 2; ++mt)
    #pragma unroll
    for (int r = 0; r < 4; ++r) {
      const f16* sr = &S16[(mt * 16 + q * 4 + r) * TS + colBase + c];
      acc[mt][0][r] += (float)sr[0];
      acc[mt][1][r] += (float)sr[16];
    }

  const f16* bp2base = Wp + WB2 + ((size_t)(q * 128 + colBase + c)) * 8;
  half8 d0 = *(const half8*)(bp2base);
  half8 d1 = *(const half8*)(bp2base + 128);

  __syncthreads();
  f16* T = S16;   // alias (S16 dead from here; same stride TS)
  #pragma unroll
  for (int mt = 0; mt < 2; ++mt)
    #pragma unroll
    for (int nt = 0; nt < 2; ++nt)
      #pragma unroll
      for (int r = 0; r < 4; ++r) {
        float v = acc[mt][nt][r];
        T[(mt * 16 + q * 4 + r) * TS + colBase + nt * 16 + c] = (f16)(v > 0.f ? v : 0.f);
      }
  __syncthreads();

  // ---- layer 2 ----
  f32x4 m2[2][2];
  {
    float b0 = be2[colBase + c], b1 = be2[colBase + 16 + c];
    #pragma unroll
    for (int mt = 0; mt < 2; ++mt) {
      m2[mt][0] = (f32x4){b0, b0, b0, b0};
      m2[mt][1] = (f32x4){b1, b1, b1, b1};
    }
  }
  #pragma unroll
  for (int kk = 0; kk < 4; ++kk) {
    half8 n0, n1;
    if (kk < 3) {
      n0 = *(const half8*)(bp2base + (kk + 1) * 4096);
      n1 = *(const half8*)(bp2base + (kk + 1) * 4096 + 128);
    }
    #pragma unroll
    for (int mt = 0; mt < 2; ++mt) {
      half8 a = *(const half8*)&T[(mt * 16 + c) * TS + kk * 32 + q * 8];
      m2[mt][0] = __builtin_amdgcn_mfma_f32_16x16x32_f16(a, d0, m2[mt][0], 0, 0, 0);
      m2[mt][1] = __builtin_amdgcn_mfma_f32_16x16x32_f16(a, d1, m2[mt][1], 0, 0, 0);
    }
    d0 = n0; d1 = n1;
  }

  // ---- relu + gate ----
  float wg0 = Wg[colBase + c], wg1 = Wg[colBase + 16 + c];
  float pd[2][4];
  #pragma unroll
  for (int mt = 0; mt < 2; ++mt)
    #pragma unroll
    for (int r = 0; r < 4; ++r) {
      float v0 = m2[mt][0][r]; v0 = v0 > 0.f ? v0 : 0.f; m2[mt][0][r] = v0;
      float v1 = m2[mt][1][r]; v1 = v1 > 0.f ? v1 : 0.f; m2[mt][1][r] = v1;
      pd[mt][r] = v0 * wg0 + v1 * wg1;
    }
  #pragma unroll
  for (int off = 1; off < 16; off <<= 1)
    #pragma unroll
    for (int mt = 0; mt < 2; ++mt)
      #pragma unroll
      for (int r = 0; r < 4; ++r)
        pd[mt][r] += __shfl_xor(pd[mt][r], off, 64);
  if (c == 0)
    #pragma unroll
    for (int mt = 0; mt < 2; ++mt)
      #pragma unroll
      for (int r = 0; r < 4; ++r)
        part[(mt * 16 + q * 4 + r) * 4 + w] = pd[mt][r];
  __syncthreads();
  if (t < EB) {
    float s = part[t * 4] + part[t * 4 + 1] + part[t * 4 + 2] + part[t * 4 + 3] + bg[0];
    eijL[t] = 1.f / (1.f + __expf(-s));
  }
  __syncthreads();

  if (perm) {
    // ---- write gated rows to T, then run-reduce equal-dst rows -> atomicAdd mi ----
    #pragma unroll
    for (int mt = 0; mt < 2; ++mt)
      #pragma unroll
      for (int r = 0; r < 4; ++r) {
        int el = mt * 16 + q * 4 + r;
        float ev = eijL[el];
        T[el * TS + colBase + c]      = (f16)(m2[mt][0][r] * ev);
        T[el * TS + colBase + 16 + c] = (f16)(m2[mt][1][r] * ev);
      }
    __syncthreads();
    int col = t & 127, half = t >> 7;
    int r0 = half * 16;
    float acc2 = 0.f;
    int dprev = dstL[r0];
    #pragma unroll
    for (int r2 = 0; r2 < 16; ++r2) {
      int rr = r0 + r2;
      acc2 += (float)T[rr * TS + col];
      int dnext = (r2 == 15) ? -1 : dstL[rr + 1];
      if (dnext != dprev) {
        atomicAdd(&mi[(size_t)dprev * HID + col], acc2);
        acc2 = 0.f;
        dprev = dnext;
      }
    }
  } else {
    #pragma unroll
    for (int mt = 0; mt < 2; ++mt)
      #pragma unroll
      for (int r = 0; r < 4; ++r) {
        int el = mt * 16 + q * 4 + r;
        float ev = eijL[el];
        float* base = mi + (size_t)dstL[el] * HID + colBase + c;
        atomicAdd(base,      m2[mt][0][r] * ev);
        atomicAdd(base + 16, m2[mt][1][r] * ev);
      }
  }
}

// ==== node MLP kernel: reads f32 mi (ws) + h16, writes out (P dead by now). ====
__global__ __launch_bounds__(256, 4) void node_kernel(
    const float* __restrict__ mi, const f16* __restrict__ h16,
    const f16* __restrict__ Wp, const float* __restrict__ bn1,
    const float* __restrict__ bn2, float* __restrict__ out) {
  __shared__ f16 Y[64 * YS];
  int t = threadIdx.x;
  int n0 = blockIdx.x * 64;
  {
    int rb = t >> 4, ch = t & 15;
    for (int p = 0; p < 4; ++p) {
      int r = p * 16 + rb;
      int g = n0 + r; if (g >= N_NODES) g = N_NODES - 1;
      const float4* s = (const float4*)(mi + (size_t)g * HID + ch * 8);
      float4 a = s[0], b = s[1];
      half8 v = {(f16)a.x, (f16)a.y, (f16)a.z, (f16)a.w,
                 (f16)b.x, (f16)b.y, (f16)b.z, (f16)b.w};
      *(half8*)&Y[r * YS + ch * 8] = v;
      *(uint4*)&Y[r * YS + 128 + ch * 8] = *(const uint4*)(h16 + (size_t)g * HID + ch * 8);
    }
  }
  __syncthreads();
  int w = t >> 6, lane = t & 63, q = lane >> 4, c = lane & 15;
  int colBase = w * 32;
  const f16* BN1 = Wp + WN1;
  const f16* BN2 = Wp + WN2;
  f32x4 acc[4][2];
  {
    float b0 = bn1[colBase + c], b1 = bn1[colBase + 16 + c];
    #pragma unroll
    for (int mt = 0; mt < 4; ++mt) {
      acc[mt][0] = (f32x4){b0, b0, b0, b0};
      acc[mt][1] = (f32x4){b1, b1, b1, b1};
    }
  }
  const f16* bn1base = BN1 + ((size_t)(q * 128 + colBase + c)) * 8;
  half8 bf0 = *(const half8*)(bn1base);
  half8 bf1 = *(const half8*)(bn1base + 128);
  #pragma unroll
  for (int ks = 0; ks < 8; ++ks) {
    half8 nb0, nb1;
    if (ks < 7) {
      nb0 = *(const half8*)(bn1base + (ks + 1) * 4096);
      nb1 = *(const half8*)(bn1base + (ks + 1) * 4096 + 128);
    }
    #pragma unroll
    for (int mt = 0; mt < 4; ++mt) {
      half8 a = *(const half8*)&Y[(mt * 16 + c) * YS + ks * 32 + q * 8];
      acc[mt][0] = __builtin_amdgcn_mfma_f32_16x16x32_f16(a, bf0, acc[mt][0], 0, 0, 0);
      acc[mt][1] = __builtin_amdgcn_mfma_f32_16x16x32_f16(a, bf1, acc[mt][1], 0, 0, 0);
    }
    bf0 = nb0; bf1 = nb1;
  }
  const f16* bn2base = BN2 + ((size_t)(q * 128 + colBase + c)) * 8;
  half8 d0 = *(const half8*)(bn2base);
  half8 d1 = *(const half8*)(bn2base + 128);
  __syncthreads();
  f16* T = Y;
  #pragma unroll
  for (int mt = 0; mt < 4; ++mt)
    #pragma unroll
    for (int nt = 0; nt < 2; ++nt)
      #pragma unroll
      for (int r = 0; r < 4; ++r) {
        float v = acc[mt][nt][r];
        T[(mt * 16 + q * 4 + r) * TS + colBase + nt * 16 + c] = (f16)(v > 0.f ? v : 0.f);
      }
  __syncthreads();
  f32x4 m2[4][2];
  {
    float b0 = bn2[colBase + c], b1 = bn2[colBase + 16 + c];
    #pragma unroll
    for (int mt = 0; mt < 4; ++mt) {
      m2[mt][0] = (f32x4){b0, b0, b0, b0};
      m2[mt][1] = (f32x4){b1, b1, b1, b1};
    }
  }
  #pragma unroll
  for (int kk = 0; kk < 4; ++kk) {
    half8 n0, n1;
    if (kk < 3) {
      n0 = *(const half8*)(bn2base + (kk + 1) * 4096);
      n1 = *(const half8*)(bn2base + (kk + 1) * 4096 + 128);
    }
    #pragma unroll
    for (int mt = 0; mt < 4; ++mt) {
      half8 a = *(const half8*)&T[(mt * 16 + c) * TS + kk * 32 + q * 8];
      m2[mt][0] = __builtin_amdgcn_mfma_f32_16x16x32_f16(a, d0, m2[mt][0], 0, 0, 0);
      m2[mt][1] = __builtin_amdgcn_mfma_f32_16x16x32_f16(a, d1, m2[mt][1], 0, 0, 0);
    }
    d0 = n0; d1 = n1;
  }
  #pragma unroll
  for (int mt = 0; mt < 4; ++mt)
    #pragma unroll
    for (int r = 0; r < 4; ++r) {
      int g = n0 + mt * 16 + q * 4 + r;
      if (g < N_NODES) {
        float* o = out + (size_t)g * HID + colBase + c;
        o[0]  = m2[mt][0][r];
        o[16] = m2[mt][1][r];
      }
    }
}

extern "C" void kernel_launch(void* const* d_in, const int* in_sizes, int n_in,
                              void* d_out, int out_size, void* d_ws, size_t ws_size,
                              hipStream_t stream) {
  const float* h    = (const float*)d_in[0];
  const int*   eidx = (const int*)d_in[1];
  const float* eattr= (const float*)d_in[2];
  const float* We1  = (const float*)d_in[3];
  const float* be1  = (const float*)d_in[4];
  const float* We2  = (const float*)d_in[5];
  const float* be2  = (const float*)d_in[6];
  const float* Wg   = (const float*)d_in[7];
  const float* bg   = (const float*)d_in[8];
  const float* Wn1  = (const float*)d_in[9];
  const float* bn1  = (const float*)d_in[10];
  const float* Wn2  = (const float*)d_in[11];
  const float* bn2  = (const float*)d_in[12];
  float* out = (float*)d_out;
  char* ws = (char*)d_ws;

  if (ws_size >= CSR_TOTAL) {
    float* mi  = (float*)(ws + OFF_MI);
    f16* h16   = (f16*)(ws + OFF_H16C);
    f16* Wp    = (f16*)(ws + OFF_WC);
    int* cnt   = (int*)(ws + OFF_CNT);
    int* cur   = (int*)(ws + OFF_CUR);
    int* perm  = (int*)(ws + OFF_PERM);
    int* bt    = (int*)(ws + OFF_BT);
    f16* P     = (f16*)out;   // P dead before node_kernel writes out

    hipMemsetAsync(mi, 0, (size_t)N_NODES * HID * sizeof(float), stream);
    pack_weights<<<400, 256, 0, stream>>>(We1, We2, Wn1, Wn2, Wp, cnt);
    precompute_kernel<<<(N_NODES + 63) / 64, 256, 0, stream>>>(h, eidx, Wp, P, h16, cnt);
    scanA<<<49, 256, 0, stream>>>(cnt, cur, bt);
    scanB<<<1, 64, 0, stream>>>(bt);
    scanC<<<49, 256, 0, stream>>>(cur, bt);
    fill_perm<<<3125, 256, 0, stream>>>(eidx, cur, perm);
    edge_kernel<<<N_EDGES / EB, 256, 0, stream>>>(P, eidx, eattr, Wp, be1, be2,
                                                  Wg, bg, mi, perm);
    node_kernel<<<(N_NODES + 63) / 64, 256, 0, stream>>>(mi, h16, Wp, bn1, bn2, out);
  } else {
    float* mi  = (float*)(ws + OFF_FMI);
    f16*   h16 = (f16*)(ws + OFF_FH16);
    f16*   Wp  = (f16*)(ws + OFF_FW);
    f16*   P   = (f16*)out;   // P dead before node_kernel writes out

    hipMemsetAsync(mi, 0, (size_t)N_NODES * HID * sizeof(float), stream);
    pack_weights<<<400, 256, 0, stream>>>(We1, We2, Wn1, Wn2, Wp, nullptr);
    precompute_kernel<<<(N_NODES + 63) / 64, 256, 0, stream>>>(h, eidx, Wp, P, h16, nullptr);
    edge_kernel<<<N_EDGES / EB, 256, 0, stream>>>(P, eidx, eattr, Wp, be1, be2,
                                                  Wg, bg, mi, nullptr);
    node_kernel<<<(N_NODES + 63) / 64, 256, 0, stream>>>(mi, h16, Wp, bn1, bn2, out);
  }
}

// Round 5
// 391.839 us; speedup vs baseline: 1.2675x; 1.0325x over previous
//
#include <hip/hip_runtime.h>

#define N_NODES 50000
#define N_EDGES 800000
#define HID 128

typedef _Float16 f16;
typedef _Float16 half8 __attribute__((ext_vector_type(8)));
typedef _Float16 half4 __attribute__((ext_vector_type(4)));
typedef _Float16 half2v __attribute__((ext_vector_type(2)));
typedef float f32x4 __attribute__((ext_vector_type(4)));
typedef float f32x2 __attribute__((ext_vector_type(2)));

// ---- CSR-path workspace layout (bytes). P (f16 [50000][256]) lives in d_out. ----
#define OFF_MI     0UL             // 50000*128*4 = 25,600,000 (f32 aggregate, zeroed in pack)
#define OFF_H16C   25600000UL      // 12,800,000
#define OFF_WC     38400000UL      // packed weights: 204,800
#define OFF_CNT    38604800UL      // 50176*4 = 200,704
#define OFF_CUR    38805504UL      // 200,704
#define OFF_E4     39006208UL      // 800000*16 = 12,800,000  (CSR-ordered {eid,dst,src,pad})
#define OFF_BT     51806208UL      // 64*4 = 256
#define CSR_TOTAL  51806464UL

// ---- fallback (atomic-path) layout ----
#define OFF_FMI  0UL
#define OFF_FH16 25600000UL
#define OFF_FW   38400000UL

#define WB1 0
#define WB2 36864
#define WN1 53248
#define WN2 86016

#define TS 136   // S16/T tile stride (f16)
#define YS 264   // node Y tile stride (256 + pad)
#define AS 40    // attr tile stride (f16): 24 attr + 8 zero + pad

#define EB 32    // edges per block

// pack weights into B-fragment layout; zero cnt and mi (CSR path) / mi (fallback)
__global__ __launch_bounds__(256) void pack_weights(
    const float* __restrict__ We1, const float* __restrict__ We2,
    const float* __restrict__ Wn1, const float* __restrict__ Wn2,
    f16* __restrict__ W, int* __restrict__ cnt, float* __restrict__ mi) {
  int i = blockIdx.x * 256 + threadIdx.x;   // 0..102399
  if (cnt && i < 50176) cnt[i] = 0;
  if (mi) {
    f32x4 z = {0.f, 0.f, 0.f, 0.f};
    for (int j = i; j < N_NODES * HID / 4; j += 102400)
      ((f32x4*)mi)[j] = z;
  }
  if (i < 36864) {                          // We1 (rows permuted: h first, attr last)
    int j = i & 7, n = (i >> 3) & 127, qk = i >> 10;
    int k = qk * 8 + j;
    float v = 0.f;
    if (k < 256) v = We1[(24 + k) * 128 + n];
    else if (k < 280) v = We1[(k - 256) * 128 + n];
    W[WB1 + i] = (f16)v;
  } else if (i < 53248) {                   // We2
    int l = i - 36864;
    int j = l & 7, n = (l >> 3) & 127, qk = l >> 10;
    W[WB2 + l] = (f16)We2[(qk * 8 + j) * 128 + n];
  } else if (i < 86016) {                   // Wn1
    int l = i - 53248;
    int j = l & 7, n = (l >> 3) & 127, qk = l >> 10;
    W[WN1 + l] = (f16)Wn1[(qk * 8 + j) * 128 + n];
  } else if (i < 102400) {                  // Wn2
    int l = i - 86016;
    int j = l & 7, n = (l >> 3) & 127, qk = l >> 10;
    W[WN2 + l] = (f16)Wn2[(qk * 8 + j) * 128 + n];
  }
}

// ==== coalesced 2-stage scan of cnt[50176] -> cur (exclusive prefix) ====
// stage A: 49 blocks x 1024 elems; int4 per thread; local exclusive scan -> cur, raw total -> bt
__global__ __launch_bounds__(256) void scanA(const int* __restrict__ cnt,
                                             int* __restrict__ cur, int* __restrict__ bt) {
  __shared__ int wsum[4];
  int t = threadIdx.x, b = blockIdx.x;
  int base = b * 1024 + t * 4;
  int4 v = *(const int4*)(cnt + base);
  int s = v.x + v.y + v.z + v.w;
  int lane = t & 63, w = t >> 6;
  int inc = s;
  #pragma unroll
  for (int off = 1; off < 64; off <<= 1) {
    int u = __shfl_up(inc, off, 64);
    if (lane >= off) inc += u;
  }
  if (lane == 63) wsum[w] = inc;
  __syncthreads();
  int wbase = 0;
  for (int i = 0; i < w; ++i) wbase += wsum[i];
  int excl = wbase + inc - s;
  int4 o;
  o.x = excl; o.y = excl + v.x; o.z = o.y + v.y; o.w = o.z + v.z;
  *(int4*)(cur + base) = o;
  if (t == 255) bt[b] = wbase + inc;
}

// stage C: block b adds sum(bt[0..b-1]) (computed in-block from raw totals)
__global__ __launch_bounds__(256) void scanC(int* __restrict__ cur, const int* __restrict__ bt) {
  __shared__ int sbase;
  int t = threadIdx.x, b = blockIdx.x;
  if (t < 64) {
    int v = (t < b) ? bt[t] : 0;
    #pragma unroll
    for (int off = 32; off; off >>= 1) v += __shfl_down(v, off, 64);
    if (t == 0) sbase = v;
  }
  __syncthreads();
  int add = sbase;
  int base = b * 1024 + t * 4;
  int4 o = *(int4*)(cur + base);
  o.x += add; o.y += add; o.z += add; o.w += add;
  *(int4*)(cur + base) = o;
}

// CSR edge records: e4[csr_pos] = {edge id, dst, src, 0} (one 16B store per edge)
__global__ __launch_bounds__(256) void fill_perm(
    const int* __restrict__ eidx, int* __restrict__ cur, int4* __restrict__ e4) {
  int i = blockIdx.x * 256 + threadIdx.x;   // 0..799999 exactly
  int d = eidx[i];
  int s = eidx[N_EDGES + i];
  int p = atomicAdd(&cur[d], 1);
  int4 rec; rec.x = i; rec.y = d; rec.z = s; rec.w = 0;
  e4[p] = rec;
}

// ==== precompute: converts h f32->f16 (writes h16), degree histogram, and
//      P[n][0:128] = h[n]@We1[24:152], P[n][128:256] = h[n]@We1[152:280] (f16). ====
__global__ __launch_bounds__(256, 4) void precompute_kernel(
    const float* __restrict__ h, const int* __restrict__ eidx,
    const f16* __restrict__ Wp, f16* __restrict__ P,
    f16* __restrict__ h16, int* __restrict__ cnt) {
  __shared__ f16 Y[64 * 136];
  int t = threadIdx.x;
  int n0 = blockIdx.x * 64;
  {
    int rb = t >> 4, ch = t & 15;
    for (int p = 0; p < 4; ++p) {
      int r = p * 16 + rb;
      int g = n0 + r; if (g >= N_NODES) g = N_NODES - 1;
      const float4* s4 = (const float4*)(h + (size_t)g * HID + ch * 8);
      float4 a = s4[0], b = s4[1];
      half8 v = {(f16)a.x, (f16)a.y, (f16)a.z, (f16)a.w,
                 (f16)b.x, (f16)b.y, (f16)b.z, (f16)b.w};
      *(half8*)&Y[r * 136 + ch * 8] = v;
      *(half8*)(h16 + (size_t)g * HID + ch * 8) = v;
    }
  }
  // fused degree histogram (grid-stride over edges)
  if (cnt) {
    for (int i = blockIdx.x * 256 + t; i < N_EDGES; i += gridDim.x * 256)
      atomicAdd(&cnt[eidx[i]], 1);
  }
  __syncthreads();
  int w = t >> 6, lane = t & 63, q = lane >> 4, c = lane & 15;
  int colBase = w * 32;
  const f16* B = Wp + WB1 + ((size_t)(q * 128 + colBase + c)) * 8;
  f32x4 aD[4][2], aS[4][2];
  #pragma unroll
  for (int mt = 0; mt < 4; ++mt) {
    aD[mt][0] = (f32x4){0, 0, 0, 0}; aD[mt][1] = (f32x4){0, 0, 0, 0};
    aS[mt][0] = (f32x4){0, 0, 0, 0}; aS[mt][1] = (f32x4){0, 0, 0, 0};
  }
  #pragma unroll
  for (int ks = 0; ks < 4; ++ks) {
    half8 bD0 = *(const half8*)(B + ks * 4096);
    half8 bD1 = *(const half8*)(B + ks * 4096 + 128);
    half8 bS0 = *(const half8*)(B + (ks + 4) * 4096);
    half8 bS1 = *(const half8*)(B + (ks + 4) * 4096 + 128);
    #pragma unroll
    for (int mt = 0; mt < 4; ++mt) {
      half8 a = *(const half8*)&Y[(mt * 16 + c) * 136 + ks * 32 + q * 8];
      aD[mt][0] = __builtin_amdgcn_mfma_f32_16x16x32_f16(a, bD0, aD[mt][0], 0, 0, 0);
      aD[mt][1] = __builtin_amdgcn_mfma_f32_16x16x32_f16(a, bD1, aD[mt][1], 0, 0, 0);
      aS[mt][0] = __builtin_amdgcn_mfma_f32_16x16x32_f16(a, bS0, aS[mt][0], 0, 0, 0);
      aS[mt][1] = __builtin_amdgcn_mfma_f32_16x16x32_f16(a, bS1, aS[mt][1], 0, 0, 0);
    }
  }
  #pragma unroll
  for (int mt = 0; mt < 4; ++mt)
    #pragma unroll
    for (int r = 0; r < 4; ++r) {
      int g = n0 + mt * 16 + q * 4 + r;
      if (g < N_NODES) {
        f16* o = P + (size_t)g * 256 + colBase + c;
        o[0]        = (f16)aD[mt][0][r];
        o[16]       = (f16)aD[mt][1][r];
        o[128]      = (f16)aS[mt][0][r];
        o[128 + 16] = (f16)aS[mt][1][r];
      }
    }
}

// ==== edge kernel: CSR-ordered e4 records (2-deep gather chain). Layer1 = attr@Wa
//      (K=32 MFMA) + f16 (Pd[dst]+Ps[src]) packed adds. In-block run-reduction over
//      equal-dst rows -> coalesced f32 atomicAdd row-sums into mi. ====
__global__ __launch_bounds__(256, 8) void edge_kernel(
    const f16* __restrict__ P, const int* __restrict__ eidx,
    const float* __restrict__ eattr,
    const f16* __restrict__ Wp, const float* __restrict__ be1,
    const float* __restrict__ be2,
    const float* __restrict__ Wg, const float* __restrict__ bg,
    float* __restrict__ mi, const int4* __restrict__ e4) {
  __shared__ f16 S16[EB * TS];       // 8,704B  (f16 Pd+Ps sums; T aliases this)
  __shared__ f16 A[EB * AS];         // 2,560B  (attr, 24 + 8 zeros)
  __shared__ float part[EB * 4];
  __shared__ float eijL[EB];
  __shared__ int dstL[EB];
  int t = threadIdx.x;
  int e0 = blockIdx.x * EB;

  if (t < EB) dstL[t] = e4 ? e4[e0 + t].y : eidx[e0 + t];

  // ---- stage S16 = Pd[dst] + Ps[src] (f16, packed adds) ----
  {
    int rb = t >> 4, ch = t & 15;
    for (int p = 0; p < 2; ++p) {
      int r = p * 16 + rb;
      int d, s;
      if (e4) {
        int4 rec = e4[e0 + r];       // 16B broadcast across the 16 lanes of this row
        d = rec.y; s = rec.z;
      } else {
        d = eidx[e0 + r]; s = eidx[N_EDGES + e0 + r];
      }
      half8 pd = *(const half8*)(P + (size_t)d * 256 + ch * 8);
      half8 ps = *(const half8*)(P + (size_t)s * 256 + 128 + ch * 8);
      *(half8*)&S16[r * TS + ch * 8] = pd + ps;
    }
  }
  // ---- stage edge_attr (cols 0..23), zeros 24..31 ----
  if (t < 192) {
    int el = t / 6, kk = t % 6;
    int e = e4 ? e4[e0 + el].x : (e0 + el);
    float4 f = *(const float4*)(eattr + (size_t)e * 24 + kk * 4);
    half4 hv = {(f16)f.x, (f16)f.y, (f16)f.z, (f16)f.w};
    *(half4*)&A[el * AS + kk * 4] = hv;
  }
  if (t < EB) { uint4 z = {0, 0, 0, 0}; *(uint4*)&A[t * AS + 24] = z; }
  __syncthreads();

  int w = t >> 6, lane = t & 63, q = lane >> 4, c = lane & 15;
  int colBase = w * 32;

  // ---- layer 1: attr GEMM (K=32, WB1 block k=256..287) + S16 add ----
  f32x4 acc[2][2];
  {
    float b0 = be1[colBase + c], b1 = be1[colBase + 16 + c];
    #pragma unroll
    for (int mt = 0; mt < 2; ++mt) {
      acc[mt][0] = (f32x4){b0, b0, b0, b0};
      acc[mt][1] = (f32x4){b1, b1, b1, b1};
    }
  }
  {
    const f16* bA = Wp + WB1 + 32768 + ((size_t)(q * 128 + colBase + c)) * 8;
    half8 b0f = *(const half8*)(bA);
    half8 b1f = *(const half8*)(bA + 128);
    #pragma unroll
    for (int mt = 0; mt < 2; ++mt) {
      half8 a = *(const half8*)&A[(mt * 16 + c) * AS + q * 8];
      acc[mt][0] = __builtin_amdgcn_mfma_f32_16x16x32_f16(a, b0f, acc[mt][0], 0, 0, 0);
      acc[mt][1] = __builtin_amdgcn_mfma_f32_16x16x32_f16(a, b1f, acc[mt][1], 0, 0, 0);
    }
  }
  #pragma unroll
  for (int mt = 0; mt < 2; ++mt)
    #pragma unroll
    for (int r = 0; r < 4; ++r) {
      const f16* sr = &S16[(mt * 16 + q * 4 + r) * TS + colBase + c];
      acc[mt][0][r] += (float)sr[0];
      acc[mt][1][r] += (float)sr[16];
    }

  const f16* bp2base = Wp + WB2 + ((size_t)(q * 128 + colBase + c)) * 8;
  half8 d0 = *(const half8*)(bp2base);
  half8 d1 = *(const half8*)(bp2base + 128);

  __syncthreads();
  f16* T = S16;   // alias (S16 dead from here; same stride TS)
  #pragma unroll
  for (int mt = 0; mt < 2; ++mt)
    #pragma unroll
    for (int nt = 0; nt < 2; ++nt)
      #pragma unroll
      for (int r = 0; r < 4; ++r) {
        float v = acc[mt][nt][r];
        T[(mt * 16 + q * 4 + r) * TS + colBase + nt * 16 + c] = (f16)(v > 0.f ? v : 0.f);
      }
  __syncthreads();

  // ---- layer 2 ----
  f32x4 m2[2][2];
  {
    float b0 = be2[colBase + c], b1 = be2[colBase + 16 + c];
    #pragma unroll
    for (int mt = 0; mt < 2; ++mt) {
      m2[mt][0] = (f32x4){b0, b0, b0, b0};
      m2[mt][1] = (f32x4){b1, b1, b1, b1};
    }
  }
  #pragma unroll
  for (int kk = 0; kk < 4; ++kk) {
    half8 n0, n1;
    if (kk < 3) {
      n0 = *(const half8*)(bp2base + (kk + 1) * 4096);
      n1 = *(const half8*)(bp2base + (kk + 1) * 4096 + 128);
    }
    #pragma unroll
    for (int mt = 0; mt < 2; ++mt) {
      half8 a = *(const half8*)&T[(mt * 16 + c) * TS + kk * 32 + q * 8];
      m2[mt][0] = __builtin_amdgcn_mfma_f32_16x16x32_f16(a, d0, m2[mt][0], 0, 0, 0);
      m2[mt][1] = __builtin_amdgcn_mfma_f32_16x16x32_f16(a, d1, m2[mt][1], 0, 0, 0);
    }
    d0 = n0; d1 = n1;
  }

  // ---- relu + gate ----
  float wg0 = Wg[colBase + c], wg1 = Wg[colBase + 16 + c];
  float pd[2][4];
  #pragma unroll
  for (int mt = 0; mt < 2; ++mt)
    #pragma unroll
    for (int r = 0; r < 4; ++r) {
      float v0 = m2[mt][0][r]; v0 = v0 > 0.f ? v0 : 0.f; m2[mt][0][r] = v0;
      float v1 = m2[mt][1][r]; v1 = v1 > 0.f ? v1 : 0.f; m2[mt][1][r] = v1;
      pd[mt][r] = v0 * wg0 + v1 * wg1;
    }
  #pragma unroll
  for (int off = 1; off < 16; off <<= 1)
    #pragma unroll
    for (int mt = 0; mt < 2; ++mt)
      #pragma unroll
      for (int r = 0; r < 4; ++r)
        pd[mt][r] += __shfl_xor(pd[mt][r], off, 64);
  if (c == 0)
    #pragma unroll
    for (int mt = 0; mt < 2; ++mt)
      #pragma unroll
      for (int r = 0; r < 4; ++r)
        part[(mt * 16 + q * 4 + r) * 4 + w] = pd[mt][r];
  __syncthreads();
  if (t < EB) {
    float s = part[t * 4] + part[t * 4 + 1] + part[t * 4 + 2] + part[t * 4 + 3] + bg[0];
    eijL[t] = 1.f / (1.f + __expf(-s));
  }
  __syncthreads();

  if (e4) {
    // ---- write gated rows to T, then run-reduce equal-dst rows -> atomicAdd mi ----
    #pragma unroll
    for (int mt = 0; mt < 2; ++mt)
      #pragma unroll
      for (int r = 0; r < 4; ++r) {
        int el = mt * 16 + q * 4 + r;
        float ev = eijL[el];
        T[el * TS + colBase + c]      = (f16)(m2[mt][0][r] * ev);
        T[el * TS + colBase + 16 + c] = (f16)(m2[mt][1][r] * ev);
      }
    __syncthreads();
    int col = t & 127, half = t >> 7;
    int r0 = half * 16;
    float acc2 = 0.f;
    int dprev = dstL[r0];
    #pragma unroll
    for (int r2 = 0; r2 < 16; ++r2) {
      int rr = r0 + r2;
      acc2 += (float)T[rr * TS + col];
      int dnext = (r2 == 15) ? -1 : dstL[rr + 1];
      if (dnext != dprev) {
        atomicAdd(&mi[(size_t)dprev * HID + col], acc2);
        acc2 = 0.f;
        dprev = dnext;
      }
    }
  } else {
    #pragma unroll
    for (int mt = 0; mt < 2; ++mt)
      #pragma unroll
      for (int r = 0; r < 4; ++r) {
        int el = mt * 16 + q * 4 + r;
        float ev = eijL[el];
        float* base = mi + (size_t)dstL[el] * HID + colBase + c;
        atomicAdd(base,      m2[mt][0][r] * ev);
        atomicAdd(base + 16, m2[mt][1][r] * ev);
      }
  }
}

// ==== node MLP kernel: reads f32 mi (ws) + h16, writes out (P dead by now). ====
__global__ __launch_bounds__(256, 4) void node_kernel(
    const float* __restrict__ mi, const f16* __restrict__ h16,
    const f16* __restrict__ Wp, const float* __restrict__ bn1,
    const float* __restrict__ bn2, float* __restrict__ out) {
  __shared__ f16 Y[64 * YS];
  int t = threadIdx.x;
  int n0 = blockIdx.x * 64;
  {
    int rb = t >> 4, ch = t & 15;
    for (int p = 0; p < 4; ++p) {
      int r = p * 16 + rb;
      int g = n0 + r; if (g >= N_NODES) g = N_NODES - 1;
      const float4* s = (const float4*)(mi + (size_t)g * HID + ch * 8);
      float4 a = s[0], b = s[1];
      half8 v = {(f16)a.x, (f16)a.y, (f16)a.z, (f16)a.w,
                 (f16)b.x, (f16)b.y, (f16)b.z, (f16)b.w};
      *(half8*)&Y[r * YS + ch * 8] = v;
      *(uint4*)&Y[r * YS + 128 + ch * 8] = *(const uint4*)(h16 + (size_t)g * HID + ch * 8);
    }
  }
  __syncthreads();
  int w = t >> 6, lane = t & 63, q = lane >> 4, c = lane & 15;
  int colBase = w * 32;
  const f16* BN1 = Wp + WN1;
  const f16* BN2 = Wp + WN2;
  f32x4 acc[4][2];
  {
    float b0 = bn1[colBase + c], b1 = bn1[colBase + 16 + c];
    #pragma unroll
    for (int mt = 0; mt < 4; ++mt) {
      acc[mt][0] = (f32x4){b0, b0, b0, b0};
      acc[mt][1] = (f32x4){b1, b1, b1, b1};
    }
  }
  const f16* bn1base = BN1 + ((size_t)(q * 128 + colBase + c)) * 8;
  half8 bf0 = *(const half8*)(bn1base);
  half8 bf1 = *(const half8*)(bn1base + 128);
  #pragma unroll
  for (int ks = 0; ks < 8; ++ks) {
    half8 nb0, nb1;
    if (ks < 7) {
      nb0 = *(const half8*)(bn1base + (ks + 1) * 4096);
      nb1 = *(const half8*)(bn1base + (ks + 1) * 4096 + 128);
    }
    #pragma unroll
    for (int mt = 0; mt < 4; ++mt) {
      half8 a = *(const half8*)&Y[(mt * 16 + c) * YS + ks * 32 + q * 8];
      acc[mt][0] = __builtin_amdgcn_mfma_f32_16x16x32_f16(a, bf0, acc[mt][0], 0, 0, 0);
      acc[mt][1] = __builtin_amdgcn_mfma_f32_16x16x32_f16(a, bf1, acc[mt][1], 0, 0, 0);
    }
    bf0 = nb0; bf1 = nb1;
  }
  const f16* bn2base = BN2 + ((size_t)(q * 128 + colBase + c)) * 8;
  half8 d0 = *(const half8*)(bn2base);
  half8 d1 = *(const half8*)(bn2base + 128);
  __syncthreads();
  f16* T = Y;
  #pragma unroll
  for (int mt = 0; mt < 4; ++mt)
    #pragma unroll
    for (int nt = 0; nt < 2; ++nt)
      #pragma unroll
      for (int r = 0; r < 4; ++r) {
        float v = acc[mt][nt][r];
        T[(mt * 16 + q * 4 + r) * TS + colBase + nt * 16 + c] = (f16)(v > 0.f ? v : 0.f);
      }
  __syncthreads();
  f32x4 m2[4][2];
  {
    float b0 = bn2[colBase + c], b1 = bn2[colBase + 16 + c];
    #pragma unroll
    for (int mt = 0; mt < 4; ++mt) {
      m2[mt][0] = (f32x4){b0, b0, b0, b0};
      m2[mt][1] = (f32x4){b1, b1, b1, b1};
    }
  }
  #pragma unroll
  for (int kk = 0; kk < 4; ++kk) {
    half8 n0, n1;
    if (kk < 3) {
      n0 = *(const half8*)(bn2base + (kk + 1) * 4096);
      n1 = *(const half8*)(bn2base + (kk + 1) * 4096 + 128);
    }
    #pragma unroll
    for (int mt = 0; mt < 4; ++mt) {
      half8 a = *(const half8*)&T[(mt * 16 + c) * TS + kk * 32 + q * 8];
      m2[mt][0] = __builtin_amdgcn_mfma_f32_16x16x32_f16(a, d0, m2[mt][0], 0, 0, 0);
      m2[mt][1] = __builtin_amdgcn_mfma_f32_16x16x32_f16(a, d1, m2[mt][1], 0, 0, 0);
    }
    d0 = n0; d1 = n1;
  }
  #pragma unroll
  for (int mt = 0; mt < 4; ++mt)
    #pragma unroll
    for (int r = 0; r < 4; ++r) {
      int g = n0 + mt * 16 + q * 4 + r;
      if (g < N_NODES) {
        float* o = out + (size_t)g * HID + colBase + c;
        o[0]  = m2[mt][0][r];
        o[16] = m2[mt][1][r];
      }
    }
}

extern "C" void kernel_launch(void* const* d_in, const int* in_sizes, int n_in,
                              void* d_out, int out_size, void* d_ws, size_t ws_size,
                              hipStream_t stream) {
  const float* h    = (const float*)d_in[0];
  const int*   eidx = (const int*)d_in[1];
  const float* eattr= (const float*)d_in[2];
  const float* We1  = (const float*)d_in[3];
  const float* be1  = (const float*)d_in[4];
  const float* We2  = (const float*)d_in[5];
  const float* be2  = (const float*)d_in[6];
  const float* Wg   = (const float*)d_in[7];
  const float* bg   = (const float*)d_in[8];
  const float* Wn1  = (const float*)d_in[9];
  const float* bn1  = (const float*)d_in[10];
  const float* Wn2  = (const float*)d_in[11];
  const float* bn2  = (const float*)d_in[12];
  float* out = (float*)d_out;
  char* ws = (char*)d_ws;

  if (ws_size >= CSR_TOTAL) {
    float* mi  = (float*)(ws + OFF_MI);
    f16* h16   = (f16*)(ws + OFF_H16C);
    f16* Wp    = (f16*)(ws + OFF_WC);
    int* cnt   = (int*)(ws + OFF_CNT);
    int* cur   = (int*)(ws + OFF_CUR);
    int4* e4   = (int4*)(ws + OFF_E4);
    int* bt    = (int*)(ws + OFF_BT);
    f16* P     = (f16*)out;   // P dead before node_kernel writes out

    pack_weights<<<400, 256, 0, stream>>>(We1, We2, Wn1, Wn2, Wp, cnt, mi);
    precompute_kernel<<<(N_NODES + 63) / 64, 256, 0, stream>>>(h, eidx, Wp, P, h16, cnt);
    scanA<<<49, 256, 0, stream>>>(cnt, cur, bt);
    scanC<<<49, 256, 0, stream>>>(cur, bt);
    fill_perm<<<3125, 256, 0, stream>>>(eidx, cur, e4);
    edge_kernel<<<N_EDGES / EB, 256, 0, stream>>>(P, eidx, eattr, Wp, be1, be2,
                                                  Wg, bg, mi, e4);
    node_kernel<<<(N_NODES + 63) / 64, 256, 0, stream>>>(mi, h16, Wp, bn1, bn2, out);
  } else {
    float* mi  = (float*)(ws + OFF_FMI);
    f16*   h16 = (f16*)(ws + OFF_FH16);
    f16*   Wp  = (f16*)(ws + OFF_FW);
    f16*   P   = (f16*)out;   // P dead before node_kernel writes out

    pack_weights<<<400, 256, 0, stream>>>(We1, We2, Wn1, Wn2, Wp, nullptr, mi);
    precompute_kernel<<<(N_NODES + 63) / 64, 256, 0, stream>>>(h, eidx, Wp, P, h16, nullptr);
    edge_kernel<<<N_EDGES / EB, 256, 0, stream>>>(P, eidx, eattr, Wp, be1, be2,
                                                  Wg, bg, mi, nullptr);
    node_kernel<<<(N_NODES + 63) / 64, 256, 0, stream>>>(mi, h16, Wp, bn1, bn2, out);
  }
}